// Round 13
// baseline (273.959 us; speedup 1.0000x reference)
//
#include <hip/hip_runtime.h>
#include <hip/hip_fp16.h>
#include <math.h>

#define D_ 128
#define K_ 1024
#define N_ 65536
#define DECAY_ 0.99f
#define OMD_ 0.01f
#define EPS_ 1e-5f
#define VQC_ 0.25f
#define M1_ 0.14f     // pair band: 2*eps(fp16 dot) + 2*keytrunc
#define M2_ 0.14f     // triple band -> full K rescan
#define BIAS_ 96.0f   // positivity shift for e2-2xe (argmin-invariant per token)
#define CLMIN_ 0.5f
#define CLMAX_ 508.0f // keys < 512 => trunc ULP 2^-5; clamped => triple-flagged
#define WSEG 32       // tokens per k_segdeq block (2 x 16-slot halves)
#define FIXB 4        // tokens batched per k_fix block-pass (Et stream /4)

typedef __attribute__((ext_vector_type(8))) _Float16 half8;
typedef __attribute__((ext_vector_type(4))) float f32x4;

// ---- workspace offsets (in 4-byte elements) ----
#define WOFF_CODE  0          // int[65536]
#define WOFF_E2    65536      // float[1024]
#define WOFF_CNT   66560      // int[1024]
#define WOFF_SSQ   67584      // float[1]  (zeroed by k_prep block 0)
#define WOFF_RCNT  67585      // int[1]    (CNT..RCNT zeroed by k_prep block 0)
#define WOFF_BASE  67648      // int[1025] (unused; scan fused into k_scatter)
#define WOFF_CURS  68736      // int[1024] zero-based scatter cursor (zeroed by prep)
#define WOFF_ORDER 69760      // int[65536]
#define WOFF_ET    136320     // float[131072] (K x D), 16B aligned
#define WOFF_PART  267392     // float[131072] (K x D) atomic segment sums
#define WOFF_CSORT 398464     // int[65536] code of each sorted slot
#define WOFF_RLIST 791680     // int[65536]
#define WOFF_EF    857216     // ushort[131072] frag-ordered fp16 of -2E

// ---- output offsets (in floats), reference return order ----
#define OOFF_Q     0          // [16,4096,128]
#define OOFF_DIFF  8388608    // scalar
#define OOFF_CODE  8388609    // [16,4096]
#define OOFF_NEMB  8454145    // [128,1024]
#define OOFF_NCS   8585217    // [1024]
#define OOFF_NMEAN 8586241    // [128,1024]

__device__ __forceinline__ unsigned umin32(unsigned a, unsigned b) { return a < b ? a : b; }
__device__ __forceinline__ unsigned umax32(unsigned a, unsigned b) { return a > b ? a : b; }

// async global->LDS 16B per lane (direct DMA, no VGPR round-trip)
__device__ __forceinline__ void gld16(const unsigned short* g, unsigned short* l) {
    __builtin_amdgcn_global_load_lds(
        (const __attribute__((address_space(1))) unsigned int*)g,
        (__attribute__((address_space(3))) unsigned int*)l, 16, 0, 0);
}

// -------------------------------------------------------------------
// Fused prep: E [D][K] -> Et [K][D], fp16 frag plane Ef of -2E, e2,
// cnt/ssq/rcnt zeroing (block 0), zc zeroing (block 1), part1 zeroing.
__launch_bounds__(256)
__global__ void k_prep(const float* __restrict__ E, float* __restrict__ Et,
                       unsigned short* __restrict__ Ef, float* __restrict__ e2,
                       int* __restrict__ cnt, int* __restrict__ zc,
                       float* __restrict__ part1) {
    __shared__ float tile[128 * 17];   // tile[d][cc], pad 17 vs 16
    __shared__ float e2s[16];
    int tid = threadIdx.x;
    int b = blockIdx.x;                // 0..63
    int c0 = b * 16;
    if (b == 0) {
        for (int i = tid; i < 1026; i += 256) cnt[i] = 0;   // cnt[1024], ssq, rcnt
    }
    if (b == 1) {
        for (int i = tid; i < 1024; i += 256) zc[i] = 0;    // scatter cursor
    }
    // zero part1 (K*D floats, 2048 per block)
    #pragma unroll
    for (int i = 0; i < 8; ++i) part1[b * 2048 + i * 256 + tid] = 0.f;
    if (tid < 16) e2s[tid] = 0.f;
    // ---- load E columns c0..c0+15 (2048 floats) ----
    #pragma unroll
    for (int i = 0; i < 8; ++i) {
        int idx = i * 256 + tid;       // 0..2047
        int d = idx >> 4, cc = idx & 15;
        tile[d * 17 + cc] = E[d * K_ + c0 + cc];
    }
    __syncthreads();
    // ---- write Et rows (coalesced, conflict-free via pad) ----
    #pragma unroll
    for (int i = 0; i < 8; ++i) {
        int idx = i * 256 + tid;
        int cc = idx >> 7, d = idx & 127;
        Et[(size_t)(c0 + cc) * D_ + d] = tile[d * 17 + cc];
    }
    // ---- Ef frags + e2 ----
    int L = tid & 63, s = tid >> 6;
    int cc = L & 15;
    int d0 = s * 32 + ((L >> 4) << 3);
    unsigned short h[8];
    float sq = 0.f;
    #pragma unroll
    for (int j = 0; j < 8; ++j) {
        float e = tile[(d0 + j) * 17 + cc];
        sq = fmaf(e, e, sq);
        h[j] = __half_as_ushort(__float2half(-2.f * e));
    }
    int T = b * 256 + tid;
    #pragma unroll
    for (int j = 0; j < 8; ++j) Ef[T * 8 + j] = h[j];
    atomicAdd(&e2s[cc], sq);
    __syncthreads();
    if (tid < 16) {
        e2[c0 + tid] = e2s[tid];
    }
}

// -------------------------------------------------------------------
// MFMA argmin — measured-best R4 configuration (55.3-55.9us across
// three independent benches): 3-buffer LDS ring (52 KB), stage-AFTER-
// compute into slot (q+2)%3 (WAR-safe: stage(q+2) issues after
// barrier(q), which all waves cross only after compute(q-1), the last
// reader of that slot), counted vmcnt(2) keeps the NEXT chunk's DMA in
// flight across every barrier. Bound (512,4): VGPR 64, no spill.
// Keys: dist' = e2 - 2x.e + 96, clamped to [0.5,508] (binade < 512 ->
// 10-bit trunc ULP <= 0.03125; clamped outliers => d1=d2=d3 => flagged).
// Top-3 certifies: d3-d1 >= M2: argmin in {i1,i2}; d2-d1 < M1 -> exact
// fp32 pair inline. d3-d1 < M2 (rare): full K rescan in k_fix.
__launch_bounds__(512, 4)
__global__ void k_argmin_mfma(const float* __restrict__ x, const unsigned short* __restrict__ Ef,
                              const float* __restrict__ e2,
                              int* __restrict__ code_i, float* __restrict__ code_f,
                              int* __restrict__ cnt, int* __restrict__ rcnt,
                              int* __restrict__ rlist, const float* __restrict__ Et) {
    __shared__ unsigned short Bs[3][8192];   // 3 x 16 KB chunk ring
    __shared__ float e2s[K_];
    int tid = threadIdx.x;
    int w = tid >> 6, L = tid & 63, quad = L >> 4, col = L & 15;
    int mg = w >> 1, ng = w & 1;             // mg 0..3 (32-token groups), ng 0..1 (code half)
    int n0 = blockIdx.x * 128;

    for (int i = tid; i < K_; i += 512) e2s[i] = e2[i];

    // ---- A fragments (32 tokens/wave, fp16) ----
    half8 ah[2][4];
    #pragma unroll
    for (int mt = 0; mt < 2; ++mt) {
        int tok = n0 + (2 * mg + mt) * 16 + col;
        #pragma unroll
        for (int s = 0; s < 4; ++s) {
            const float* p = x + (size_t)tok * D_ + s * 32 + quad * 8;
            float4 u0 = *(const float4*)(p);
            float4 u1 = *(const float4*)(p + 4);
            ah[mt][s][0] = (_Float16)u0.x; ah[mt][s][1] = (_Float16)u0.y;
            ah[mt][s][2] = (_Float16)u0.z; ah[mt][s][3] = (_Float16)u0.w;
            ah[mt][s][4] = (_Float16)u1.x; ah[mt][s][5] = (_Float16)u1.y;
            ah[mt][s][6] = (_Float16)u1.z; ah[mt][s][7] = (_Float16)u1.w;
        }
    }

    unsigned k1[2][4], k2[2][4], k3[2][4];
    #pragma unroll
    for (int mt = 0; mt < 2; ++mt)
        #pragma unroll
        for (int r = 0; r < 4; ++r) {
            k1[mt][r] = 0xFFFFFFFFu; k2[mt][r] = 0xFFFFFFFFu; k3[mt][r] = 0xFFFFFFFFu;
        }

    __syncthreads();                          // e2s visible; nothing else in flight

    // ---- prologue: stage chunks 0,1 into slots 0,1 (2 ops each/wave) ----
    #pragma unroll
    for (int i = 0; i < 2; ++i) {
        int o = (w * 2 + i) * 512;
        gld16(Ef + o + L * 8, &Bs[0][o]);
    }
    #pragma unroll
    for (int i = 0; i < 2; ++i) {
        int o = (w * 2 + i) * 512;
        gld16(Ef + 8192 + o + L * 8, &Bs[1][o]);
    }

    #pragma unroll
    for (int q = 0; q < 16; ++q) {
        // outstanding here: chunk q (2 ops) + chunk q+1 (2 ops).
        // vmcnt(2) retires MY chunk-q loads; barrier => ALL waves' retired.
        if (q < 15) asm volatile("s_waitcnt vmcnt(2)" ::: "memory");
        else        asm volatile("s_waitcnt vmcnt(0)" ::: "memory");
        __builtin_amdgcn_s_barrier();
        asm volatile("" ::: "memory");

        const unsigned short* Bp = &Bs[q % 3][0];

        // ---- acc init = e2[code] + BIAS ----
        float evb[2];
        #pragma unroll
        for (int nn = 0; nn < 2; ++nn)
            evb[nn] = e2s[q * 64 + (2 * ng + nn) * 16 + col] + BIAS_;
        f32x4 acc[2][2];
        #pragma unroll
        for (int mt = 0; mt < 2; ++mt)
            #pragma unroll
            for (int nn = 0; nn < 2; ++nn)
                #pragma unroll
                for (int r = 0; r < 4; ++r)
                    acc[mt][nn][r] = evb[nn];

        // ---- 16 MFMA: 4 k-steps x 2 n-subs x 2 m-tiles ----
        #pragma unroll
        for (int s = 0; s < 4; ++s) {
            half8 bh[2];
            #pragma unroll
            for (int nn = 0; nn < 2; ++nn) {
                int off = (((2 * ng + nn) * 4 + s) * 64 + L) * 8;
                bh[nn] = *(const half8*)(Bp + off);
            }
            #pragma unroll
            for (int nn = 0; nn < 2; ++nn)
                #pragma unroll
                for (int mt = 0; mt < 2; ++mt)
                    acc[mt][nn] = __builtin_amdgcn_mfma_f32_16x16x32_f16(ah[mt][s], bh[nn], acc[mt][nn], 0, 0, 0);
        }

        // ---- clamp to [0.5,508] + packed-key top-3 insert ----
        #pragma unroll
        for (int nn = 0; nn < 2; ++nn) {
            unsigned cb = (unsigned)(q * 64 + (2 * ng + nn) * 16 + col);
            #pragma unroll
            for (int mt = 0; mt < 2; ++mt)
                #pragma unroll
                for (int r = 0; r < 4; ++r) {
                    float dc = fminf(fmaxf(acc[mt][nn][r], CLMIN_), CLMAX_);
                    unsigned key = (__float_as_uint(dc) & 0xFFFFFC00u) | cb;
                    unsigned m1 = umax32(k1[mt][r], key);
                    k1[mt][r]   = umin32(k1[mt][r], key);
                    unsigned m2 = umax32(k2[mt][r], m1);
                    k2[mt][r]   = umin32(k2[mt][r], m1);
                    k3[mt][r]   = umin32(k3[mt][r], m2);
                }
        }

        // ---- stage chunk q+2 into slot (q+2)%3 (WAR-safe) ----
        if (q < 14) {
            const unsigned short* src = Ef + (q + 2) * 8192;
            int sl = (q + 2) % 3;
            #pragma unroll
            for (int i = 0; i < 2; ++i) {
                int o = (w * 2 + i) * 512;
                gld16(src + o + L * 8, &Bs[sl][o]);
            }
        }
    }

    // ---- cross-lane merge of sorted triples over 16 cols ----
    __syncthreads();
    unsigned* mk1 = (unsigned*)&Bs[0][0];     // [128 tokens][2 halves] x 3
    unsigned* mk2 = mk1 + 256;
    unsigned* mk3 = mk2 + 256;

    #pragma unroll
    for (int mt = 0; mt < 2; ++mt) {
        #pragma unroll
        for (int r = 0; r < 4; ++r) {
            unsigned a = k1[mt][r], b = k2[mt][r], c = k3[mt][r];
            #pragma unroll
            for (int m = 1; m < 16; m <<= 1) {
                unsigned ao = (unsigned)__shfl_xor((int)a, m);
                unsigned bo = (unsigned)__shfl_xor((int)b, m);
                unsigned co = (unsigned)__shfl_xor((int)c, m);
                unsigned t1 = umax32(a, ao);
                a           = umin32(a, ao);
                unsigned s2 = umin32(b, bo);
                unsigned u  = umax32(t1, s2);
                b           = umin32(t1, s2);
                c           = umin32(u, umin32(c, co));
            }
            if (col == 0) {
                int tl = (2 * mg + mt) * 16 + quad * 4 + r;
                mk1[tl * 2 + ng] = a;
                mk2[tl * 2 + ng] = b;
                mk3[tl * 2 + ng] = c;
            }
        }
    }
    __syncthreads();
    if (tid < 128) {
        unsigned a1 = mk1[tid * 2], b1 = mk1[tid * 2 + 1];
        unsigned a2 = mk2[tid * 2], b2 = mk2[tid * 2 + 1];
        unsigned a3 = mk3[tid * 2], b3 = mk3[tid * 2 + 1];
        unsigned t1 = umax32(a1, b1);
        unsigned kk1 = umin32(a1, b1);
        unsigned s2 = umin32(a2, b2);
        unsigned kk2 = umin32(t1, s2);
        unsigned u  = umax32(t1, s2);
        unsigned kk3 = umin32(u, umin32(a3, b3));

        int i1 = (int)(kk1 & 1023u), i2 = (int)(kk2 & 1023u);
        float d1 = __uint_as_float(kk1 & 0xFFFFFC00u);
        float d2 = __uint_as_float(kk2 & 0xFFFFFC00u);
        float d3 = __uint_as_float(kk3 & 0xFFFFFC00u);
        int tok = n0 + tid;

        if (d3 - d1 < M2_) {
            // 3+ codes inside the uncertainty band: full exact rescan later
            code_i[tok] = i1;
            code_f[tok] = (float)i1;
            atomicAdd(cnt + i1, 1);
            int p = atomicAdd(rcnt, 1);
            rlist[p] = tok;
        } else {
            int win = i1;
            if (d2 - d1 < M1_) {
                // exact fp32 pair decision, inline (true argmin is i1 or i2)
                const float* xr = x  + (size_t)tok * D_;
                const float* ea = Et + (size_t)i1 * D_;
                const float* eb = Et + (size_t)i2 * D_;
                float s1 = 0.f, sB = 0.f;
                #pragma unroll 4
                for (int dd = 0; dd < D_; dd += 4) {
                    float4 xv = *(const float4*)(xr + dd);
                    float4 av = *(const float4*)(ea + dd);
                    float4 bv = *(const float4*)(eb + dd);
                    s1 = fmaf(xv.x, av.x, s1); s1 = fmaf(xv.y, av.y, s1);
                    s1 = fmaf(xv.z, av.z, s1); s1 = fmaf(xv.w, av.w, s1);
                    sB = fmaf(xv.x, bv.x, sB); sB = fmaf(xv.y, bv.y, sB);
                    sB = fmaf(xv.z, bv.z, sB); sB = fmaf(xv.w, bv.w, sB);
                }
                float ex1 = e2s[i1] - 2.f * s1;
                float ex2 = e2s[i2] - 2.f * sB;
                if (ex2 < ex1 || (ex2 == ex1 && i2 < i1)) win = i2;
            }
            code_i[tok] = win;
            code_f[tok] = (float)win;
            atomicAdd(cnt + win, 1);
        }
    }
}

// -------------------------------------------------------------------
// exact fp32 re-argmin for triple-ambiguous tokens, BATCHED 4/pass:
// k_fix cost scales as rcnt x 512KB of Et re-stream (R1 measured this
// exact structure at 62.7us with ~5-8k flagged). Staging 4 tokens' x in
// LDS and streaming Et once per 4 cuts that traffic 4x. Slot scheme
// unchanged (8 x 32-lane groups, codes c == slot mod 8, c ascending =>
// first-min per slot; final merge tie-breaks by index).
__launch_bounds__(256)
__global__ void k_fix(const float* __restrict__ x, const float* __restrict__ Et,
                      const float* __restrict__ e2, const int* __restrict__ rcnt,
                      const int* __restrict__ rlist, int* __restrict__ code_i,
                      float* __restrict__ code_f, int* __restrict__ cnt) {
    __shared__ float4 xs[FIXB][32];
    __shared__ float  e2s[K_];
    __shared__ float  sd[8][FIXB];
    __shared__ int    si[8][FIXB];
    int tid = threadIdx.x;
    int lane = tid & 63, w = tid >> 6;
    int half = lane >> 5;
    int q32  = lane & 31;
    int slot = w * 2 + half;     // 0..7: codes c ≡ slot (mod 8)
    int nr = *rcnt;
    for (int i = tid; i < K_; i += 256) e2s[i] = e2[i];

    for (int base = blockIdx.x * FIXB; base < nr; base += gridDim.x * FIXB) {
        int ntok = nr - base; if (ntok > FIXB) ntok = FIXB;
        __syncthreads();                       // xs/sd free (prev iter merged)
        if (tid < 32 * FIXB) {
            int j = tid >> 5, qq = tid & 31;
            if (j < ntok)
                xs[j][qq] = ((const float4*)(x + (size_t)rlist[base + j] * D_))[qq];
        }
        __syncthreads();

        float bd[FIXB]; int bb[FIXB];
        #pragma unroll
        for (int j = 0; j < FIXB; ++j) { bd[j] = INFINITY; bb[j] = 0; }

        for (int c0 = 0; c0 < K_; c0 += 8) {
            int c = c0 + slot;
            float4 e = ((const float4*)(Et + (size_t)c * D_))[q32];
            float ec = e2s[c];
            #pragma unroll
            for (int j = 0; j < FIXB; ++j) {
                float4 xv = xs[j][q32];
                float dot = xv.x * e.x + xv.y * e.y + xv.z * e.z + xv.w * e.w;
                dot += __shfl_xor(dot, 1);
                dot += __shfl_xor(dot, 2);
                dot += __shfl_xor(dot, 4);
                dot += __shfl_xor(dot, 8);
                dot += __shfl_xor(dot, 16);
                float dist = ec - 2.f * dot;
                if (dist < bd[j]) { bd[j] = dist; bb[j] = c; }  // c ascending
            }
        }
        if (q32 == 0) {
            #pragma unroll
            for (int j = 0; j < FIXB; ++j) { sd[slot][j] = bd[j]; si[slot][j] = bb[j]; }
        }
        __syncthreads();
        if (tid < ntok) {
            int j = tid;
            float fb = sd[0][j]; int fi = si[0][j];
            #pragma unroll
            for (int s = 1; s < 8; ++s) {
                if (sd[s][j] < fb || (sd[s][j] == fb && si[s][j] < fi)) {
                    fb = sd[s][j]; fi = si[s][j];
                }
            }
            int tok = rlist[base + j];
            int ob = code_i[tok];
            if (fi != ob) {
                code_i[tok] = fi;
                code_f[tok] = (float)fi;
                atomicAdd(cnt + ob, -1);
                atomicAdd(cnt + fi, 1);
            }
        }
    }
}

// -------------------------------------------------------------------
// Fused scan+scatter: each block redundantly computes the exclusive
// scan of cnt[1024] in LDS (kills the serial 1-block k_scan launch),
// then scatters its 256 tokens via base[c] + atomicAdd(zc+c,1).
__launch_bounds__(256)
__global__ void k_scatter(const int* __restrict__ cnt, const int* __restrict__ code_i,
                          int* __restrict__ zc, int* __restrict__ order,
                          int* __restrict__ csort) {
    __shared__ int sbase[1024];
    __shared__ int wtot[4];
    int t = threadIdx.x;
    int lane = t & 63, wv = t >> 6;
    int c4[4];
    #pragma unroll
    for (int j = 0; j < 4; ++j) c4[j] = cnt[4 * t + j];
    int s = c4[0] + c4[1] + c4[2] + c4[3];
    int ps = s;
    #pragma unroll
    for (int m = 1; m < 64; m <<= 1) {
        int o = __shfl_up(ps, m);
        if (lane >= m) ps += o;
    }
    if (lane == 63) wtot[wv] = ps;
    __syncthreads();
    int woff = 0;
    for (int i = 0; i < 4; ++i) if (i < wv) woff += wtot[i];
    int run = woff + ps - s;
    #pragma unroll
    for (int j = 0; j < 4; ++j) {
        sbase[4 * t + j] = run;    // exclusive base of code 4t+j
        run += c4[j];
    }
    __syncthreads();

    int n = blockIdx.x * 256 + t;
    int c = code_i[n];
    int pos = sbase[c] + atomicAdd(zc + c, 1);
    order[pos] = n;
    csort[pos] = c;
}

// -------------------------------------------------------------------
// UNIFORM-WORK fused segment-sum + dequant/ST/ssq, 256 threads:
// block i owns sorted slots [32i,32i+32) as TWO independent 16-slot
// halves (tid>>7), each with its own running-sum flush chain (flushes
// are atomic -> correct regardless of which half flushes).
__launch_bounds__(256)
__global__ void k_segdeq(const float* __restrict__ x, const float* __restrict__ Et,
                         const int* __restrict__ order, const int* __restrict__ csort,
                         float* __restrict__ part1, float* __restrict__ outq,
                         float* __restrict__ ssqp) {
    __shared__ int sn[WSEG], sc[WSEG];
    __shared__ float wsum[4];
    int tid = threadIdx.x;
    int d = tid & 127;
    int h = tid >> 7;                       // half 0/1
    int i0 = blockIdx.x * WSEG;
    if (tid < WSEG) { sn[tid] = order[i0 + tid]; sc[tid] = csort[i0 + tid]; }
    __syncthreads();
    int s0 = h * 16;
    int cprev = sc[s0];
    float eq = Et[(size_t)cprev * D_ + d];
    float acc = 0.f, ssql = 0.f;
    float xv = x[(size_t)sn[s0] * D_ + d];
    #pragma unroll 4
    for (int j = 0; j < 16; ++j) {
        int sj = s0 + j;
        float xn = (j < 15) ? x[(size_t)sn[sj + 1] * D_ + d] : 0.f;  // prefetch
        int c = sc[sj];
        if (c != cprev) {                      // wave-uniform branch
            atomicAdd(&part1[(size_t)cprev * D_ + d], acc);
            acc = 0.f;
            eq = Et[(size_t)c * D_ + d];
            cprev = c;
        }
        float qv = xv + (eq - xv);             // reference fp32 rounding
        outq[(size_t)sn[sj] * D_ + d] = qv;
        float t = qv - xv;
        ssql = fmaf(t, t, ssql);
        acc += xv;
        xv = xn;
    }
    atomicAdd(&part1[(size_t)cprev * D_ + d], acc);

    // block-reduce ssql (4 waves of 64) -> one global atomic
    #pragma unroll
    for (int off = 32; off > 0; off >>= 1) ssql += __shfl_down(ssql, off);
    if ((tid & 63) == 0) wsum[tid >> 6] = ssql;
    __syncthreads();
    if (tid == 0) atomicAdd(ssqp, (wsum[0] + wsum[1]) + (wsum[2] + wsum[3]));
}

// -------------------------------------------------------------------
// fused stats + embed: each block redundantly reduces n; block 0 also
// writes out_ncs + out_diff. Then EMA mean + divide for its 256 elems.
__launch_bounds__(256)
__global__ void k_embed(const float* __restrict__ em, const float* __restrict__ part1,
                        const int* __restrict__ cnt, const float* __restrict__ csz,
                        const float* __restrict__ ssqp, float* __restrict__ out_nmean,
                        float* __restrict__ out_nemb, float* __restrict__ out_ncs,
                        float* __restrict__ out_diff) {
    int tid = threadIdx.x;
    __shared__ float red[256];

    // ---- n = sum_k ncs_k (redundant per block) ----
    float ls = 0.f;
    for (int j = tid; j < K_; j += 256) ls += csz[j] * DECAY_ + OMD_ * (float)cnt[j];
    red[tid] = ls;
    __syncthreads();
    for (int off = 128; off > 0; off >>= 1) {
        if (tid < off) red[tid] += red[tid + off];
        __syncthreads();
    }
    float n = red[0];
    __syncthreads();

    if (blockIdx.x == 0) {
        for (int j = tid; j < K_; j += 256)
            out_ncs[j] = csz[j] * DECAY_ + OMD_ * (float)cnt[j];
        if (tid == 0) *out_diff = VQC_ * ssqp[0] / (float)(N_ * D_);
    }

    int i = blockIdx.x * 256 + tid;           // over D*K, layout [D][K]
    int k = i & (K_ - 1);
    int d = i >> 10;
    float ncs_k = csz[k] * DECAY_ + OMD_ * (float)cnt[k];
    float csk = (ncs_k + EPS_) / (n + (float)K_ * EPS_) * n;
    float es = part1[(size_t)k * D_ + d];
    float nm = em[i] * DECAY_ + OMD_ * es;
    out_nmean[i] = nm;
    out_nemb[i]  = nm / csk;
}

// -------------------------------------------------------------------
extern "C" void kernel_launch(void* const* d_in, const int* in_sizes, int n_in,
                              void* d_out, int out_size, void* d_ws, size_t ws_size,
                              hipStream_t stream) {
    const float* x   = (const float*)d_in[0];   // [16,4096,128]
    const float* E   = (const float*)d_in[1];   // [128,1024]
    const float* csz = (const float*)d_in[2];   // [1024]
    const float* em  = (const float*)d_in[3];   // [128,1024]
    float* out = (float*)d_out;
    float* W   = (float*)d_ws;

    int*   code_i = (int*)(W + WOFF_CODE);
    float* e2     = W + WOFF_E2;
    int*   cnt    = (int*)(W + WOFF_CNT);
    float* ssqp   = W + WOFF_SSQ;
    int*   rcnt   = (int*)(W + WOFF_RCNT);
    int*   zc     = (int*)(W + WOFF_CURS);
    int*   order  = (int*)(W + WOFF_ORDER);
    float* Et     = W + WOFF_ET;
    float* part1  = W + WOFF_PART;
    int*   csort  = (int*)(W + WOFF_CSORT);
    int*   rlist  = (int*)(W + WOFF_RLIST);
    unsigned short* Ef = (unsigned short*)(W + WOFF_EF);

    k_prep<<<64, 256, 0, stream>>>(E, Et, Ef, e2, cnt, zc, part1);
    k_argmin_mfma<<<N_ / 128, 512, 0, stream>>>(x, Ef, e2, code_i,
                                                out + OOFF_CODE, cnt, rcnt, rlist, Et);
    k_fix<<<1024, 256, 0, stream>>>(x, Et, e2, rcnt, rlist, code_i, out + OOFF_CODE, cnt);
    k_scatter<<<N_ / 256, 256, 0, stream>>>(cnt, code_i, zc, order, csort);
    k_segdeq<<<N_ / WSEG, 256, 0, stream>>>(x, Et, order, csort, part1,
                                            out + OOFF_Q, ssqp);
    k_embed<<<(D_ * K_) / 256, 256, 0, stream>>>(em, part1, cnt, csz, ssqp,
                                                 out + OOFF_NMEAN, out + OOFF_NEMB,
                                                 out + OOFF_NCS, out + OOFF_DIFF);
}

// Round 15
// 222.959 us; speedup vs baseline: 1.2287x; 1.2287x over previous
//
#include <hip/hip_runtime.h>
#include <hip/hip_fp16.h>
#include <math.h>

#define D_ 128
#define K_ 1024
#define N_ 65536
#define DECAY_ 0.99f
#define OMD_ 0.01f
#define EPS_ 1e-5f
#define VQC_ 0.25f
#define M1_ 0.14f     // pair band: 2*eps(fp16 dot) + 2*keytrunc
#define M2_ 0.14f     // triple band -> full K rescan
#define BIAS_ 96.0f   // positivity shift for e2-2xe (argmin-invariant per token)
#define CLMIN_ 0.5f
#define CLMAX_ 508.0f // keys < 512 => trunc ULP 2^-5; clamped => triple-flagged
#define WSEG 32       // tokens per k_segdeq block (2 x 16-slot halves)

typedef __attribute__((ext_vector_type(8))) _Float16 half8;
typedef __attribute__((ext_vector_type(4))) float f32x4;

// ---- workspace offsets (in 4-byte elements) ----
#define WOFF_CODE  0          // int[65536]
#define WOFF_E2    65536      // float[1024]
#define WOFF_CNT   66560      // int[1024]
#define WOFF_SSQ   67584      // float[1]  (zeroed by k_prep block 0)
#define WOFF_RCNT  67585      // int[1]    (CNT..RCNT zeroed by k_prep block 0)
#define WOFF_BASE  67648      // int[1025] (unused; scan fused into k_scatter)
#define WOFF_CURS  68736      // int[1024] zero-based scatter cursor (zeroed by prep)
#define WOFF_ORDER 69760      // int[65536]
#define WOFF_ET    136320     // float[131072] (K x D), 16B aligned
#define WOFF_PART  267392     // float[131072] (K x D) atomic segment sums
#define WOFF_CSORT 398464     // int[65536] code of each sorted slot
#define WOFF_RLIST 791680     // int[65536]
#define WOFF_EF    857216     // ushort[131072] frag-ordered fp16 of -2E

// ---- output offsets (in floats), reference return order ----
#define OOFF_Q     0          // [16,4096,128]
#define OOFF_DIFF  8388608    // scalar
#define OOFF_CODE  8388609    // [16,4096]
#define OOFF_NEMB  8454145    // [128,1024]
#define OOFF_NCS   8585217    // [1024]
#define OOFF_NMEAN 8586241    // [128,1024]

__device__ __forceinline__ unsigned umin32(unsigned a, unsigned b) { return a < b ? a : b; }
__device__ __forceinline__ unsigned umax32(unsigned a, unsigned b) { return a > b ? a : b; }

// async global->LDS 16B per lane (direct DMA, no VGPR round-trip)
__device__ __forceinline__ void gld16(const unsigned short* g, unsigned short* l) {
    __builtin_amdgcn_global_load_lds(
        (const __attribute__((address_space(1))) unsigned int*)g,
        (__attribute__((address_space(3))) unsigned int*)l, 16, 0, 0);
}

// -------------------------------------------------------------------
// Fused prep: E [D][K] -> Et [K][D], fp16 frag plane Ef of -2E, e2,
// cnt/ssq/rcnt zeroing (block 0), zc zeroing (block 1), part1 zeroing.
__launch_bounds__(256)
__global__ void k_prep(const float* __restrict__ E, float* __restrict__ Et,
                       unsigned short* __restrict__ Ef, float* __restrict__ e2,
                       int* __restrict__ cnt, int* __restrict__ zc,
                       float* __restrict__ part1) {
    __shared__ float tile[128 * 17];   // tile[d][cc], pad 17 vs 16
    __shared__ float e2s[16];
    int tid = threadIdx.x;
    int b = blockIdx.x;                // 0..63
    int c0 = b * 16;
    if (b == 0) {
        for (int i = tid; i < 1026; i += 256) cnt[i] = 0;   // cnt[1024], ssq, rcnt
    }
    if (b == 1) {
        for (int i = tid; i < 1024; i += 256) zc[i] = 0;    // scatter cursor
    }
    // zero part1 (K*D floats, 2048 per block)
    #pragma unroll
    for (int i = 0; i < 8; ++i) part1[b * 2048 + i * 256 + tid] = 0.f;
    if (tid < 16) e2s[tid] = 0.f;
    // ---- load E columns c0..c0+15 (2048 floats) ----
    #pragma unroll
    for (int i = 0; i < 8; ++i) {
        int idx = i * 256 + tid;       // 0..2047
        int d = idx >> 4, cc = idx & 15;
        tile[d * 17 + cc] = E[d * K_ + c0 + cc];
    }
    __syncthreads();
    // ---- write Et rows (coalesced, conflict-free via pad) ----
    #pragma unroll
    for (int i = 0; i < 8; ++i) {
        int idx = i * 256 + tid;
        int cc = idx >> 7, d = idx & 127;
        Et[(size_t)(c0 + cc) * D_ + d] = tile[d * 17 + cc];
    }
    // ---- Ef frags + e2 ----
    int L = tid & 63, s = tid >> 6;
    int cc = L & 15;
    int d0 = s * 32 + ((L >> 4) << 3);
    unsigned short h[8];
    float sq = 0.f;
    #pragma unroll
    for (int j = 0; j < 8; ++j) {
        float e = tile[(d0 + j) * 17 + cc];
        sq = fmaf(e, e, sq);
        h[j] = __half_as_ushort(__float2half(-2.f * e));
    }
    int T = b * 256 + tid;
    #pragma unroll
    for (int j = 0; j < 8; ++j) Ef[T * 8 + j] = h[j];
    atomicAdd(&e2s[cc], sq);
    __syncthreads();
    if (tid < 16) {
        e2[c0 + tid] = e2s[tid];
    }
}

// -------------------------------------------------------------------
// MFMA argmin — measured-best R4 configuration (55.3-55.9us across
// three independent benches): 3-buffer LDS ring (52 KB), stage-AFTER-
// compute into slot (q+2)%3 (WAR-safe: stage(q+2) issues after
// barrier(q), which all waves cross only after compute(q-1), the last
// reader of that slot), counted vmcnt(2) keeps the NEXT chunk's DMA in
// flight across every barrier. Bound (512,4): VGPR 64, no spill.
// Keys: dist' = e2 - 2x.e + 96, clamped to [0.5,508] (binade < 512 ->
// 10-bit trunc ULP <= 0.03125; clamped outliers => d1=d2=d3 => flagged).
// Top-3 certifies: d3-d1 >= M2: argmin in {i1,i2}; d2-d1 < M1 -> exact
// fp32 pair inline. d3-d1 < M2 (rare): full K rescan in k_fix.
__launch_bounds__(512, 4)
__global__ void k_argmin_mfma(const float* __restrict__ x, const unsigned short* __restrict__ Ef,
                              const float* __restrict__ e2,
                              int* __restrict__ code_i, float* __restrict__ code_f,
                              int* __restrict__ cnt, int* __restrict__ rcnt,
                              int* __restrict__ rlist, const float* __restrict__ Et) {
    __shared__ unsigned short Bs[3][8192];   // 3 x 16 KB chunk ring
    __shared__ float e2s[K_];
    int tid = threadIdx.x;
    int w = tid >> 6, L = tid & 63, quad = L >> 4, col = L & 15;
    int mg = w >> 1, ng = w & 1;             // mg 0..3 (32-token groups), ng 0..1 (code half)
    int n0 = blockIdx.x * 128;

    for (int i = tid; i < K_; i += 512) e2s[i] = e2[i];

    // ---- A fragments (32 tokens/wave, fp16) ----
    half8 ah[2][4];
    #pragma unroll
    for (int mt = 0; mt < 2; ++mt) {
        int tok = n0 + (2 * mg + mt) * 16 + col;
        #pragma unroll
        for (int s = 0; s < 4; ++s) {
            const float* p = x + (size_t)tok * D_ + s * 32 + quad * 8;
            float4 u0 = *(const float4*)(p);
            float4 u1 = *(const float4*)(p + 4);
            ah[mt][s][0] = (_Float16)u0.x; ah[mt][s][1] = (_Float16)u0.y;
            ah[mt][s][2] = (_Float16)u0.z; ah[mt][s][3] = (_Float16)u0.w;
            ah[mt][s][4] = (_Float16)u1.x; ah[mt][s][5] = (_Float16)u1.y;
            ah[mt][s][6] = (_Float16)u1.z; ah[mt][s][7] = (_Float16)u1.w;
        }
    }

    unsigned k1[2][4], k2[2][4], k3[2][4];
    #pragma unroll
    for (int mt = 0; mt < 2; ++mt)
        #pragma unroll
        for (int r = 0; r < 4; ++r) {
            k1[mt][r] = 0xFFFFFFFFu; k2[mt][r] = 0xFFFFFFFFu; k3[mt][r] = 0xFFFFFFFFu;
        }

    __syncthreads();                          // e2s visible; nothing else in flight

    // ---- prologue: stage chunks 0,1 into slots 0,1 (2 ops each/wave) ----
    #pragma unroll
    for (int i = 0; i < 2; ++i) {
        int o = (w * 2 + i) * 512;
        gld16(Ef + o + L * 8, &Bs[0][o]);
    }
    #pragma unroll
    for (int i = 0; i < 2; ++i) {
        int o = (w * 2 + i) * 512;
        gld16(Ef + 8192 + o + L * 8, &Bs[1][o]);
    }

    #pragma unroll
    for (int q = 0; q < 16; ++q) {
        // outstanding here: chunk q (2 ops) + chunk q+1 (2 ops).
        // vmcnt(2) retires MY chunk-q loads; barrier => ALL waves' retired.
        if (q < 15) asm volatile("s_waitcnt vmcnt(2)" ::: "memory");
        else        asm volatile("s_waitcnt vmcnt(0)" ::: "memory");
        __builtin_amdgcn_s_barrier();
        asm volatile("" ::: "memory");

        const unsigned short* Bp = &Bs[q % 3][0];

        // ---- acc init = e2[code] + BIAS ----
        float evb[2];
        #pragma unroll
        for (int nn = 0; nn < 2; ++nn)
            evb[nn] = e2s[q * 64 + (2 * ng + nn) * 16 + col] + BIAS_;
        f32x4 acc[2][2];
        #pragma unroll
        for (int mt = 0; mt < 2; ++mt)
            #pragma unroll
            for (int nn = 0; nn < 2; ++nn)
                #pragma unroll
                for (int r = 0; r < 4; ++r)
                    acc[mt][nn][r] = evb[nn];

        // ---- 16 MFMA: 4 k-steps x 2 n-subs x 2 m-tiles ----
        #pragma unroll
        for (int s = 0; s < 4; ++s) {
            half8 bh[2];
            #pragma unroll
            for (int nn = 0; nn < 2; ++nn) {
                int off = (((2 * ng + nn) * 4 + s) * 64 + L) * 8;
                bh[nn] = *(const half8*)(Bp + off);
            }
            #pragma unroll
            for (int nn = 0; nn < 2; ++nn)
                #pragma unroll
                for (int mt = 0; mt < 2; ++mt)
                    acc[mt][nn] = __builtin_amdgcn_mfma_f32_16x16x32_f16(ah[mt][s], bh[nn], acc[mt][nn], 0, 0, 0);
        }

        // ---- clamp to [0.5,508] + packed-key top-3 insert ----
        #pragma unroll
        for (int nn = 0; nn < 2; ++nn) {
            unsigned cb = (unsigned)(q * 64 + (2 * ng + nn) * 16 + col);
            #pragma unroll
            for (int mt = 0; mt < 2; ++mt)
                #pragma unroll
                for (int r = 0; r < 4; ++r) {
                    float dc = fminf(fmaxf(acc[mt][nn][r], CLMIN_), CLMAX_);
                    unsigned key = (__float_as_uint(dc) & 0xFFFFFC00u) | cb;
                    unsigned m1 = umax32(k1[mt][r], key);
                    k1[mt][r]   = umin32(k1[mt][r], key);
                    unsigned m2 = umax32(k2[mt][r], m1);
                    k2[mt][r]   = umin32(k2[mt][r], m1);
                    k3[mt][r]   = umin32(k3[mt][r], m2);
                }
        }

        // ---- stage chunk q+2 into slot (q+2)%3 (WAR-safe) ----
        if (q < 14) {
            const unsigned short* src = Ef + (q + 2) * 8192;
            int sl = (q + 2) % 3;
            #pragma unroll
            for (int i = 0; i < 2; ++i) {
                int o = (w * 2 + i) * 512;
                gld16(src + o + L * 8, &Bs[sl][o]);
            }
        }
    }

    // ---- cross-lane merge of sorted triples over 16 cols ----
    __syncthreads();
    unsigned* mk1 = (unsigned*)&Bs[0][0];     // [128 tokens][2 halves] x 3
    unsigned* mk2 = mk1 + 256;
    unsigned* mk3 = mk2 + 256;

    #pragma unroll
    for (int mt = 0; mt < 2; ++mt) {
        #pragma unroll
        for (int r = 0; r < 4; ++r) {
            unsigned a = k1[mt][r], b = k2[mt][r], c = k3[mt][r];
            #pragma unroll
            for (int m = 1; m < 16; m <<= 1) {
                unsigned ao = (unsigned)__shfl_xor((int)a, m);
                unsigned bo = (unsigned)__shfl_xor((int)b, m);
                unsigned co = (unsigned)__shfl_xor((int)c, m);
                unsigned t1 = umax32(a, ao);
                a           = umin32(a, ao);
                unsigned s2 = umin32(b, bo);
                unsigned u  = umax32(t1, s2);
                b           = umin32(t1, s2);
                c           = umin32(u, umin32(c, co));
            }
            if (col == 0) {
                int tl = (2 * mg + mt) * 16 + quad * 4 + r;
                mk1[tl * 2 + ng] = a;
                mk2[tl * 2 + ng] = b;
                mk3[tl * 2 + ng] = c;
            }
        }
    }
    __syncthreads();
    if (tid < 128) {
        unsigned a1 = mk1[tid * 2], b1 = mk1[tid * 2 + 1];
        unsigned a2 = mk2[tid * 2], b2 = mk2[tid * 2 + 1];
        unsigned a3 = mk3[tid * 2], b3 = mk3[tid * 2 + 1];
        unsigned t1 = umax32(a1, b1);
        unsigned kk1 = umin32(a1, b1);
        unsigned s2 = umin32(a2, b2);
        unsigned kk2 = umin32(t1, s2);
        unsigned u  = umax32(t1, s2);
        unsigned kk3 = umin32(u, umin32(a3, b3));

        int i1 = (int)(kk1 & 1023u), i2 = (int)(kk2 & 1023u);
        float d1 = __uint_as_float(kk1 & 0xFFFFFC00u);
        float d2 = __uint_as_float(kk2 & 0xFFFFFC00u);
        float d3 = __uint_as_float(kk3 & 0xFFFFFC00u);
        int tok = n0 + tid;

        if (d3 - d1 < M2_) {
            // 3+ codes inside the uncertainty band: full exact rescan later
            code_i[tok] = i1;
            code_f[tok] = (float)i1;
            atomicAdd(cnt + i1, 1);
            int p = atomicAdd(rcnt, 1);
            rlist[p] = tok;
        } else {
            int win = i1;
            if (d2 - d1 < M1_) {
                // exact fp32 pair decision, inline (true argmin is i1 or i2)
                const float* xr = x  + (size_t)tok * D_;
                const float* ea = Et + (size_t)i1 * D_;
                const float* eb = Et + (size_t)i2 * D_;
                float s1 = 0.f, sB = 0.f;
                #pragma unroll 4
                for (int dd = 0; dd < D_; dd += 4) {
                    float4 xv = *(const float4*)(xr + dd);
                    float4 av = *(const float4*)(ea + dd);
                    float4 bv = *(const float4*)(eb + dd);
                    s1 = fmaf(xv.x, av.x, s1); s1 = fmaf(xv.y, av.y, s1);
                    s1 = fmaf(xv.z, av.z, s1); s1 = fmaf(xv.w, av.w, s1);
                    sB = fmaf(xv.x, bv.x, sB); sB = fmaf(xv.y, bv.y, sB);
                    sB = fmaf(xv.z, bv.z, sB); sB = fmaf(xv.w, bv.w, sB);
                }
                float ex1 = e2s[i1] - 2.f * s1;
                float ex2 = e2s[i2] - 2.f * sB;
                if (ex2 < ex1 || (ex2 == ex1 && i2 < i1)) win = i2;
            }
            code_i[tok] = win;
            code_f[tok] = (float)win;
            atomicAdd(cnt + win, 1);
        }
    }
}

// -------------------------------------------------------------------
// exact fp32 re-argmin for triple-ambiguous tokens. LATENCY-OPTIMIZED:
// R13 showed k_fix is latency-bound (FETCH 1.3MB, VALU 0.4%), serial
// chain = dependent L2 Et load -> 5-deep shuffle reduce x 128 iters
// (~16us/token-pass); batching tokens cut parallelism and DOUBLED time.
// Fix: one token per block-pass (max parallel blocks, grid 2048 so
// rcnt~2500 fits in <=2 passes) + c0-loop unrolled 4x with all 4 Et
// loads issued UP FRONT (4 independent load+reduce chains in flight ->
// per-iter latency /~4) + e2 staged in LDS (removes 2nd dependent load).
// Compare order ca<cb<cc<cd keeps first-min (lowest index) semantics.
__launch_bounds__(256)
__global__ void k_fix(const float* __restrict__ x, const float* __restrict__ Et,
                      const float* __restrict__ e2, const int* __restrict__ rcnt,
                      const int* __restrict__ rlist, int* __restrict__ code_i,
                      float* __restrict__ code_f, int* __restrict__ cnt) {
    __shared__ float4 xs[32];
    __shared__ float  e2s[K_];
    __shared__ float  sd[8];
    __shared__ int    si[8];
    int tid = threadIdx.x;
    int lane = tid & 63, w = tid >> 6;
    int half = lane >> 5;
    int q32  = lane & 31;
    int slot = w * 2 + half;     // 0..7: codes c ≡ slot (mod 8)
    int nr = *rcnt;
    for (int i = tid; i < K_; i += 256) e2s[i] = e2[i];

    for (int it = blockIdx.x; it < nr; it += gridDim.x) {
        __syncthreads();                      // e2s ready / prev iter merged
        int tok = rlist[it];
        if (tid < 32) xs[tid] = ((const float4*)(x + (size_t)tok * D_))[tid];
        __syncthreads();
        float4 xv = xs[q32];
        float bd = INFINITY; int bb = 0;
        for (int c0 = 0; c0 < K_; c0 += 32) {
            int ca = c0 + slot, cb = ca + 8, cc = ca + 16, cd = ca + 24;
            // 4 independent Et loads issued up front (break load-use chain)
            float4 ea = ((const float4*)(Et + (size_t)ca * D_))[q32];
            float4 eb = ((const float4*)(Et + (size_t)cb * D_))[q32];
            float4 ec = ((const float4*)(Et + (size_t)cc * D_))[q32];
            float4 ed = ((const float4*)(Et + (size_t)cd * D_))[q32];
            float da = xv.x * ea.x + xv.y * ea.y + xv.z * ea.z + xv.w * ea.w;
            float db = xv.x * eb.x + xv.y * eb.y + xv.z * eb.z + xv.w * eb.w;
            float dc = xv.x * ec.x + xv.y * ec.y + xv.z * ec.z + xv.w * ec.w;
            float dd = xv.x * ed.x + xv.y * ed.y + xv.z * ed.z + xv.w * ed.w;
            #pragma unroll
            for (int m = 1; m <= 16; m <<= 1) {   // 4 interleaved reduce chains
                da += __shfl_xor(da, m);
                db += __shfl_xor(db, m);
                dc += __shfl_xor(dc, m);
                dd += __shfl_xor(dd, m);
            }
            float A = e2s[ca] - 2.f * da;
            float B = e2s[cb] - 2.f * db;
            float C = e2s[cc] - 2.f * dc;
            float Dv = e2s[cd] - 2.f * dd;
            if (A  < bd) { bd = A;  bb = ca; }   // ascending code order =>
            if (B  < bd) { bd = B;  bb = cb; }   // strict < keeps first-min
            if (C  < bd) { bd = C;  bb = cc; }
            if (Dv < bd) { bd = Dv; bb = cd; }
        }
        if (q32 == 0) { sd[slot] = bd; si[slot] = bb; }
        __syncthreads();
        if (tid == 0) {
            float fb = sd[0]; int fi = si[0];
            #pragma unroll
            for (int s = 1; s < 8; ++s) {
                if (sd[s] < fb || (sd[s] == fb && si[s] < fi)) { fb = sd[s]; fi = si[s]; }
            }
            int ob = code_i[tok];
            if (fi != ob) {
                code_i[tok] = fi;
                code_f[tok] = (float)fi;
                atomicAdd(cnt + ob, -1);
                atomicAdd(cnt + fi, 1);
            }
        }
    }
}

// -------------------------------------------------------------------
// Fused scan+scatter: each block redundantly computes the exclusive
// scan of cnt[1024] in LDS (kills the serial 1-block k_scan launch),
// then scatters its 256 tokens via base[c] + atomicAdd(zc+c,1).
__launch_bounds__(256)
__global__ void k_scatter(const int* __restrict__ cnt, const int* __restrict__ code_i,
                          int* __restrict__ zc, int* __restrict__ order,
                          int* __restrict__ csort) {
    __shared__ int sbase[1024];
    __shared__ int wtot[4];
    int t = threadIdx.x;
    int lane = t & 63, wv = t >> 6;
    int c4[4];
    #pragma unroll
    for (int j = 0; j < 4; ++j) c4[j] = cnt[4 * t + j];
    int s = c4[0] + c4[1] + c4[2] + c4[3];
    int ps = s;
    #pragma unroll
    for (int m = 1; m < 64; m <<= 1) {
        int o = __shfl_up(ps, m);
        if (lane >= m) ps += o;
    }
    if (lane == 63) wtot[wv] = ps;
    __syncthreads();
    int woff = 0;
    for (int i = 0; i < 4; ++i) if (i < wv) woff += wtot[i];
    int run = woff + ps - s;
    #pragma unroll
    for (int j = 0; j < 4; ++j) {
        sbase[4 * t + j] = run;    // exclusive base of code 4t+j
        run += c4[j];
    }
    __syncthreads();

    int n = blockIdx.x * 256 + t;
    int c = code_i[n];
    int pos = sbase[c] + atomicAdd(zc + c, 1);
    order[pos] = n;
    csort[pos] = c;
}

// -------------------------------------------------------------------
// UNIFORM-WORK fused segment-sum + dequant/ST/ssq, 256 threads:
// block i owns sorted slots [32i,32i+32) as TWO independent 16-slot
// halves (tid>>7), each with its own running-sum flush chain (flushes
// are atomic -> correct regardless of which half flushes).
__launch_bounds__(256)
__global__ void k_segdeq(const float* __restrict__ x, const float* __restrict__ Et,
                         const int* __restrict__ order, const int* __restrict__ csort,
                         float* __restrict__ part1, float* __restrict__ outq,
                         float* __restrict__ ssqp) {
    __shared__ int sn[WSEG], sc[WSEG];
    __shared__ float wsum[4];
    int tid = threadIdx.x;
    int d = tid & 127;
    int h = tid >> 7;                       // half 0/1
    int i0 = blockIdx.x * WSEG;
    if (tid < WSEG) { sn[tid] = order[i0 + tid]; sc[tid] = csort[i0 + tid]; }
    __syncthreads();
    int s0 = h * 16;
    int cprev = sc[s0];
    float eq = Et[(size_t)cprev * D_ + d];
    float acc = 0.f, ssql = 0.f;
    float xv = x[(size_t)sn[s0] * D_ + d];
    #pragma unroll 4
    for (int j = 0; j < 16; ++j) {
        int sj = s0 + j;
        float xn = (j < 15) ? x[(size_t)sn[sj + 1] * D_ + d] : 0.f;  // prefetch
        int c = sc[sj];
        if (c != cprev) {                      // wave-uniform branch
            atomicAdd(&part1[(size_t)cprev * D_ + d], acc);
            acc = 0.f;
            eq = Et[(size_t)c * D_ + d];
            cprev = c;
        }
        float qv = xv + (eq - xv);             // reference fp32 rounding
        outq[(size_t)sn[sj] * D_ + d] = qv;
        float t = qv - xv;
        ssql = fmaf(t, t, ssql);
        acc += xv;
        xv = xn;
    }
    atomicAdd(&part1[(size_t)cprev * D_ + d], acc);

    // block-reduce ssql (4 waves of 64) -> one global atomic
    #pragma unroll
    for (int off = 32; off > 0; off >>= 1) ssql += __shfl_down(ssql, off);
    if ((tid & 63) == 0) wsum[tid >> 6] = ssql;
    __syncthreads();
    if (tid == 0) atomicAdd(ssqp, (wsum[0] + wsum[1]) + (wsum[2] + wsum[3]));
}

// -------------------------------------------------------------------
// fused stats + embed: each block redundantly reduces n; block 0 also
// writes out_ncs + out_diff. Then EMA mean + divide for its 256 elems.
__launch_bounds__(256)
__global__ void k_embed(const float* __restrict__ em, const float* __restrict__ part1,
                        const int* __restrict__ cnt, const float* __restrict__ csz,
                        const float* __restrict__ ssqp, float* __restrict__ out_nmean,
                        float* __restrict__ out_nemb, float* __restrict__ out_ncs,
                        float* __restrict__ out_diff) {
    int tid = threadIdx.x;
    __shared__ float red[256];

    // ---- n = sum_k ncs_k (redundant per block) ----
    float ls = 0.f;
    for (int j = tid; j < K_; j += 256) ls += csz[j] * DECAY_ + OMD_ * (float)cnt[j];
    red[tid] = ls;
    __syncthreads();
    for (int off = 128; off > 0; off >>= 1) {
        if (tid < off) red[tid] += red[tid + off];
        __syncthreads();
    }
    float n = red[0];
    __syncthreads();

    if (blockIdx.x == 0) {
        for (int j = tid; j < K_; j += 256)
            out_ncs[j] = csz[j] * DECAY_ + OMD_ * (float)cnt[j];
        if (tid == 0) *out_diff = VQC_ * ssqp[0] / (float)(N_ * D_);
    }

    int i = blockIdx.x * 256 + tid;           // over D*K, layout [D][K]
    int k = i & (K_ - 1);
    int d = i >> 10;
    float ncs_k = csz[k] * DECAY_ + OMD_ * (float)cnt[k];
    float csk = (ncs_k + EPS_) / (n + (float)K_ * EPS_) * n;
    float es = part1[(size_t)k * D_ + d];
    float nm = em[i] * DECAY_ + OMD_ * es;
    out_nmean[i] = nm;
    out_nemb[i]  = nm / csk;
}

// -------------------------------------------------------------------
extern "C" void kernel_launch(void* const* d_in, const int* in_sizes, int n_in,
                              void* d_out, int out_size, void* d_ws, size_t ws_size,
                              hipStream_t stream) {
    const float* x   = (const float*)d_in[0];   // [16,4096,128]
    const float* E   = (const float*)d_in[1];   // [128,1024]
    const float* csz = (const float*)d_in[2];   // [1024]
    const float* em  = (const float*)d_in[3];   // [128,1024]
    float* out = (float*)d_out;
    float* W   = (float*)d_ws;

    int*   code_i = (int*)(W + WOFF_CODE);
    float* e2     = W + WOFF_E2;
    int*   cnt    = (int*)(W + WOFF_CNT);
    float* ssqp   = W + WOFF_SSQ;
    int*   rcnt   = (int*)(W + WOFF_RCNT);
    int*   zc     = (int*)(W + WOFF_CURS);
    int*   order  = (int*)(W + WOFF_ORDER);
    float* Et     = W + WOFF_ET;
    float* part1  = W + WOFF_PART;
    int*   csort  = (int*)(W + WOFF_CSORT);
    int*   rlist  = (int*)(W + WOFF_RLIST);
    unsigned short* Ef = (unsigned short*)(W + WOFF_EF);

    k_prep<<<64, 256, 0, stream>>>(E, Et, Ef, e2, cnt, zc, part1);
    k_argmin_mfma<<<N_ / 128, 512, 0, stream>>>(x, Ef, e2, code_i,
                                                out + OOFF_CODE, cnt, rcnt, rlist, Et);
    k_fix<<<2048, 256, 0, stream>>>(x, Et, e2, rcnt, rlist, code_i, out + OOFF_CODE, cnt);
    k_scatter<<<N_ / 256, 256, 0, stream>>>(cnt, code_i, zc, order, csort);
    k_segdeq<<<N_ / WSEG, 256, 0, stream>>>(x, Et, order, csort, part1,
                                            out + OOFF_Q, ssqp);
    k_embed<<<(D_ * K_) / 256, 256, 0, stream>>>(em, part1, cnt, csz, ssqp,
                                                 out + OOFF_NMEAN, out + OOFF_NEMB,
                                                 out + OOFF_NCS, out + OOFF_DIFF);
}

// Round 16
// 210.172 us; speedup vs baseline: 1.3035x; 1.0608x over previous
//
#include <hip/hip_runtime.h>
#include <hip/hip_fp16.h>
#include <math.h>

#define D_ 128
#define K_ 1024
#define N_ 65536
#define DECAY_ 0.99f
#define OMD_ 0.01f
#define EPS_ 1e-5f
#define VQC_ 0.25f
#define M1_ 0.14f     // pair band: 2*eps(fp16 dot) + 2*keytrunc
#define M2_ 0.14f     // triple band -> full K rescan
#define BIAS_ 96.0f   // positivity shift for e2-2xe (argmin-invariant per token)
#define CLMIN_ 0.5f
#define CLMAX_ 508.0f // keys < 512 => trunc ULP 2^-5; clamped => triple-flagged
#define WSEG 32       // tokens per k_segsum block (2 x 16-slot halves)

typedef __attribute__((ext_vector_type(8))) _Float16 half8;
typedef __attribute__((ext_vector_type(4))) float f32x4;

// ---- workspace offsets (in 4-byte elements) ----
#define WOFF_CODE  0          // int[65536]
#define WOFF_E2    65536      // float[1024]
#define WOFF_CNT   66560      // int[1024]
#define WOFF_SSQ   67584      // float[1]  (zeroed by k_prep block 0)
#define WOFF_RCNT  67585      // int[1]    (CNT..RCNT zeroed by k_prep block 0)
#define WOFF_BASE  67648      // int[1025] (unused; scan fused into k_scatter)
#define WOFF_CURS  68736      // int[1024] zero-based scatter cursor (zeroed by prep)
#define WOFF_ORDER 69760      // int[65536]
#define WOFF_ET    136320     // float[131072] (K x D), 16B aligned
#define WOFF_PART  267392     // float[131072] (K x D) atomic segment sums
#define WOFF_CSORT 398464     // int[65536] code of each sorted slot
#define WOFF_RLIST 791680     // int[65536]
#define WOFF_EF    857216     // ushort[131072] frag-ordered fp16 of -2E

// ---- output offsets (in floats), reference return order ----
#define OOFF_Q     0          // [16,4096,128]
#define OOFF_DIFF  8388608    // scalar
#define OOFF_CODE  8388609    // [16,4096]
#define OOFF_NEMB  8454145    // [128,1024]
#define OOFF_NCS   8585217    // [1024]
#define OOFF_NMEAN 8586241    // [128,1024]

__device__ __forceinline__ unsigned umin32(unsigned a, unsigned b) { return a < b ? a : b; }
__device__ __forceinline__ unsigned umax32(unsigned a, unsigned b) { return a > b ? a : b; }

// async global->LDS 16B per lane (direct DMA, no VGPR round-trip)
__device__ __forceinline__ void gld16(const unsigned short* g, unsigned short* l) {
    __builtin_amdgcn_global_load_lds(
        (const __attribute__((address_space(1))) unsigned int*)g,
        (__attribute__((address_space(3))) unsigned int*)l, 16, 0, 0);
}

// -------------------------------------------------------------------
// Fused prep: E [D][K] -> Et [K][D], fp16 frag plane Ef of -2E, e2,
// cnt/ssq/rcnt zeroing (block 0), zc zeroing (block 1), part1 zeroing.
__launch_bounds__(256)
__global__ void k_prep(const float* __restrict__ E, float* __restrict__ Et,
                       unsigned short* __restrict__ Ef, float* __restrict__ e2,
                       int* __restrict__ cnt, int* __restrict__ zc,
                       float* __restrict__ part1) {
    __shared__ float tile[128 * 17];   // tile[d][cc], pad 17 vs 16
    __shared__ float e2s[16];
    int tid = threadIdx.x;
    int b = blockIdx.x;                // 0..63
    int c0 = b * 16;
    if (b == 0) {
        for (int i = tid; i < 1026; i += 256) cnt[i] = 0;   // cnt[1024], ssq, rcnt
    }
    if (b == 1) {
        for (int i = tid; i < 1024; i += 256) zc[i] = 0;    // scatter cursor
    }
    // zero part1 (K*D floats, 2048 per block)
    #pragma unroll
    for (int i = 0; i < 8; ++i) part1[b * 2048 + i * 256 + tid] = 0.f;
    if (tid < 16) e2s[tid] = 0.f;
    // ---- load E columns c0..c0+15 (2048 floats) ----
    #pragma unroll
    for (int i = 0; i < 8; ++i) {
        int idx = i * 256 + tid;       // 0..2047
        int d = idx >> 4, cc = idx & 15;
        tile[d * 17 + cc] = E[d * K_ + c0 + cc];
    }
    __syncthreads();
    // ---- write Et rows (coalesced, conflict-free via pad) ----
    #pragma unroll
    for (int i = 0; i < 8; ++i) {
        int idx = i * 256 + tid;
        int cc = idx >> 7, d = idx & 127;
        Et[(size_t)(c0 + cc) * D_ + d] = tile[d * 17 + cc];
    }
    // ---- Ef frags + e2 ----
    int L = tid & 63, s = tid >> 6;
    int cc = L & 15;
    int d0 = s * 32 + ((L >> 4) << 3);
    unsigned short h[8];
    float sq = 0.f;
    #pragma unroll
    for (int j = 0; j < 8; ++j) {
        float e = tile[(d0 + j) * 17 + cc];
        sq = fmaf(e, e, sq);
        h[j] = __half_as_ushort(__float2half(-2.f * e));
    }
    int T = b * 256 + tid;
    #pragma unroll
    for (int j = 0; j < 8; ++j) Ef[T * 8 + j] = h[j];
    atomicAdd(&e2s[cc], sq);
    __syncthreads();
    if (tid < 16) {
        e2[c0 + tid] = e2s[tid];
    }
}

// -------------------------------------------------------------------
// MFMA argmin + FUSED DEQUANT: main loop = measured-best R4 config
// (3-ring, vmcnt(2), stage-after-compute, bound (512,4)). NEW: the
// epilogue also writes outq (straight-through rows, formula
// q = x + (e-x) matching reference fp32 rounding) and accumulates ssq
// — the kernel is 60% stall-bound (Mfma 11% + VALU 30%), so the 32MB
// outq write rides the existing bubbles, and segdeq sheds half its
// traffic. Flagged tokens get i1's row; k_fix patches outq/ssq for the
// ~2% it re-decides.
__launch_bounds__(512, 4)
__global__ void k_argmin_mfma(const float* __restrict__ x, const unsigned short* __restrict__ Ef,
                              const float* __restrict__ e2,
                              int* __restrict__ code_i, float* __restrict__ code_f,
                              int* __restrict__ cnt, int* __restrict__ rcnt,
                              int* __restrict__ rlist, const float* __restrict__ Et,
                              float* __restrict__ outq, float* __restrict__ ssqp) {
    __shared__ unsigned short Bs[3][8192];   // 3 x 16 KB chunk ring
    __shared__ float e2s[K_];
    __shared__ float ws[8];
    int tid = threadIdx.x;
    int w = tid >> 6, L = tid & 63, quad = L >> 4, col = L & 15;
    int mg = w >> 1, ng = w & 1;             // mg 0..3 (32-token groups), ng 0..1 (code half)
    int n0 = blockIdx.x * 128;

    for (int i = tid; i < K_; i += 512) e2s[i] = e2[i];

    // ---- A fragments (32 tokens/wave, fp16) ----
    half8 ah[2][4];
    #pragma unroll
    for (int mt = 0; mt < 2; ++mt) {
        int tok = n0 + (2 * mg + mt) * 16 + col;
        #pragma unroll
        for (int s = 0; s < 4; ++s) {
            const float* p = x + (size_t)tok * D_ + s * 32 + quad * 8;
            float4 u0 = *(const float4*)(p);
            float4 u1 = *(const float4*)(p + 4);
            ah[mt][s][0] = (_Float16)u0.x; ah[mt][s][1] = (_Float16)u0.y;
            ah[mt][s][2] = (_Float16)u0.z; ah[mt][s][3] = (_Float16)u0.w;
            ah[mt][s][4] = (_Float16)u1.x; ah[mt][s][5] = (_Float16)u1.y;
            ah[mt][s][6] = (_Float16)u1.z; ah[mt][s][7] = (_Float16)u1.w;
        }
    }

    unsigned k1[2][4], k2[2][4], k3[2][4];
    #pragma unroll
    for (int mt = 0; mt < 2; ++mt)
        #pragma unroll
        for (int r = 0; r < 4; ++r) {
            k1[mt][r] = 0xFFFFFFFFu; k2[mt][r] = 0xFFFFFFFFu; k3[mt][r] = 0xFFFFFFFFu;
        }

    __syncthreads();                          // e2s visible; nothing else in flight

    // ---- prologue: stage chunks 0,1 into slots 0,1 (2 ops each/wave) ----
    #pragma unroll
    for (int i = 0; i < 2; ++i) {
        int o = (w * 2 + i) * 512;
        gld16(Ef + o + L * 8, &Bs[0][o]);
    }
    #pragma unroll
    for (int i = 0; i < 2; ++i) {
        int o = (w * 2 + i) * 512;
        gld16(Ef + 8192 + o + L * 8, &Bs[1][o]);
    }

    #pragma unroll
    for (int q = 0; q < 16; ++q) {
        // outstanding here: chunk q (2 ops) + chunk q+1 (2 ops).
        // vmcnt(2) retires MY chunk-q loads; barrier => ALL waves' retired.
        if (q < 15) asm volatile("s_waitcnt vmcnt(2)" ::: "memory");
        else        asm volatile("s_waitcnt vmcnt(0)" ::: "memory");
        __builtin_amdgcn_s_barrier();
        asm volatile("" ::: "memory");

        const unsigned short* Bp = &Bs[q % 3][0];

        // ---- acc init = e2[code] + BIAS ----
        float evb[2];
        #pragma unroll
        for (int nn = 0; nn < 2; ++nn)
            evb[nn] = e2s[q * 64 + (2 * ng + nn) * 16 + col] + BIAS_;
        f32x4 acc[2][2];
        #pragma unroll
        for (int mt = 0; mt < 2; ++mt)
            #pragma unroll
            for (int nn = 0; nn < 2; ++nn)
                #pragma unroll
                for (int r = 0; r < 4; ++r)
                    acc[mt][nn][r] = evb[nn];

        // ---- 16 MFMA: 4 k-steps x 2 n-subs x 2 m-tiles ----
        #pragma unroll
        for (int s = 0; s < 4; ++s) {
            half8 bh[2];
            #pragma unroll
            for (int nn = 0; nn < 2; ++nn) {
                int off = (((2 * ng + nn) * 4 + s) * 64 + L) * 8;
                bh[nn] = *(const half8*)(Bp + off);
            }
            #pragma unroll
            for (int nn = 0; nn < 2; ++nn)
                #pragma unroll
                for (int mt = 0; mt < 2; ++mt)
                    acc[mt][nn] = __builtin_amdgcn_mfma_f32_16x16x32_f16(ah[mt][s], bh[nn], acc[mt][nn], 0, 0, 0);
        }

        // ---- clamp to [0.5,508] + packed-key top-3 insert ----
        #pragma unroll
        for (int nn = 0; nn < 2; ++nn) {
            unsigned cb = (unsigned)(q * 64 + (2 * ng + nn) * 16 + col);
            #pragma unroll
            for (int mt = 0; mt < 2; ++mt)
                #pragma unroll
                for (int r = 0; r < 4; ++r) {
                    float dc = fminf(fmaxf(acc[mt][nn][r], CLMIN_), CLMAX_);
                    unsigned key = (__float_as_uint(dc) & 0xFFFFFC00u) | cb;
                    unsigned m1 = umax32(k1[mt][r], key);
                    k1[mt][r]   = umin32(k1[mt][r], key);
                    unsigned m2 = umax32(k2[mt][r], m1);
                    k2[mt][r]   = umin32(k2[mt][r], m1);
                    k3[mt][r]   = umin32(k3[mt][r], m2);
                }
        }

        // ---- stage chunk q+2 into slot (q+2)%3 (WAR-safe) ----
        if (q < 14) {
            const unsigned short* src = Ef + (q + 2) * 8192;
            int sl = (q + 2) % 3;
            #pragma unroll
            for (int i = 0; i < 2; ++i) {
                int o = (w * 2 + i) * 512;
                gld16(src + o + L * 8, &Bs[sl][o]);
            }
        }
    }

    // ---- cross-lane merge of sorted triples over 16 cols ----
    __syncthreads();
    unsigned* mk1 = (unsigned*)&Bs[0][0];     // [128 tokens][2 halves] x 3
    unsigned* mk2 = mk1 + 256;
    unsigned* mk3 = mk2 + 256;
    int* codeL    = (int*)(mk3 + 256);        // decided code per token slot

    #pragma unroll
    for (int mt = 0; mt < 2; ++mt) {
        #pragma unroll
        for (int r = 0; r < 4; ++r) {
            unsigned a = k1[mt][r], b = k2[mt][r], c = k3[mt][r];
            #pragma unroll
            for (int m = 1; m < 16; m <<= 1) {
                unsigned ao = (unsigned)__shfl_xor((int)a, m);
                unsigned bo = (unsigned)__shfl_xor((int)b, m);
                unsigned co = (unsigned)__shfl_xor((int)c, m);
                unsigned t1 = umax32(a, ao);
                a           = umin32(a, ao);
                unsigned s2 = umin32(b, bo);
                unsigned u  = umax32(t1, s2);
                b           = umin32(t1, s2);
                c           = umin32(u, umin32(c, co));
            }
            if (col == 0) {
                int tl = (2 * mg + mt) * 16 + quad * 4 + r;
                mk1[tl * 2 + ng] = a;
                mk2[tl * 2 + ng] = b;
                mk3[tl * 2 + ng] = c;
            }
        }
    }
    __syncthreads();
    if (tid < 128) {
        unsigned a1 = mk1[tid * 2], b1 = mk1[tid * 2 + 1];
        unsigned a2 = mk2[tid * 2], b2 = mk2[tid * 2 + 1];
        unsigned a3 = mk3[tid * 2], b3 = mk3[tid * 2 + 1];
        unsigned t1 = umax32(a1, b1);
        unsigned kk1 = umin32(a1, b1);
        unsigned s2 = umin32(a2, b2);
        unsigned kk2 = umin32(t1, s2);
        unsigned u  = umax32(t1, s2);
        unsigned kk3 = umin32(u, umin32(a3, b3));

        int i1 = (int)(kk1 & 1023u), i2 = (int)(kk2 & 1023u);
        float d1 = __uint_as_float(kk1 & 0xFFFFFC00u);
        float d2 = __uint_as_float(kk2 & 0xFFFFFC00u);
        float d3 = __uint_as_float(kk3 & 0xFFFFFC00u);
        int tok = n0 + tid;

        if (d3 - d1 < M2_) {
            // 3+ codes inside the uncertainty band: full exact rescan later
            code_i[tok] = i1;
            code_f[tok] = (float)i1;
            codeL[tid] = i1;
            atomicAdd(cnt + i1, 1);
            int p = atomicAdd(rcnt, 1);
            rlist[p] = tok;
        } else {
            int win = i1;
            if (d2 - d1 < M1_) {
                // exact fp32 pair decision, inline (true argmin is i1 or i2)
                const float* xr = x  + (size_t)tok * D_;
                const float* ea = Et + (size_t)i1 * D_;
                const float* eb = Et + (size_t)i2 * D_;
                float s1 = 0.f, sB = 0.f;
                #pragma unroll 4
                for (int dd = 0; dd < D_; dd += 4) {
                    float4 xv = *(const float4*)(xr + dd);
                    float4 av = *(const float4*)(ea + dd);
                    float4 bv = *(const float4*)(eb + dd);
                    s1 = fmaf(xv.x, av.x, s1); s1 = fmaf(xv.y, av.y, s1);
                    s1 = fmaf(xv.z, av.z, s1); s1 = fmaf(xv.w, av.w, s1);
                    sB = fmaf(xv.x, bv.x, sB); sB = fmaf(xv.y, bv.y, sB);
                    sB = fmaf(xv.z, bv.z, sB); sB = fmaf(xv.w, bv.w, sB);
                }
                float ex1 = e2s[i1] - 2.f * s1;
                float ex2 = e2s[i2] - 2.f * sB;
                if (ex2 < ex1 || (ex2 == ex1 && i2 < i1)) win = i2;
            }
            code_i[tok] = win;
            code_f[tok] = (float)win;
            codeL[tid] = win;
            atomicAdd(cnt + win, 1);
        }
    }
    __syncthreads();

    // ---- fused dequant/ST + ssq for this block's 128 tokens ----
    // thread t: token t>>2, dims (t&3)*32 .. +31 (8 x float4). x and Et
    // rows are L2-hot (read moments ago); outq is the only HBM traffic.
    {
        int tk = tid >> 2;
        int db = (tid & 3) * 32;
        int tok = n0 + tk;
        int c = codeL[tk];
        const float* xr = x   + (size_t)tok * D_ + db;
        const float* er = Et  + (size_t)c   * D_ + db;
        float*       qr = outq + (size_t)tok * D_ + db;
        float ssql = 0.f;
        #pragma unroll
        for (int k2 = 0; k2 < 8; ++k2) {
            float4 xv = *(const float4*)(xr + k2 * 4);
            float4 ev = *(const float4*)(er + k2 * 4);
            float4 qv;
            qv.x = xv.x + (ev.x - xv.x);      // reference fp32 rounding
            qv.y = xv.y + (ev.y - xv.y);
            qv.z = xv.z + (ev.z - xv.z);
            qv.w = xv.w + (ev.w - xv.w);
            *(float4*)(qr + k2 * 4) = qv;
            float t0 = qv.x - xv.x, t1 = qv.y - xv.y;
            float t2 = qv.z - xv.z, t3 = qv.w - xv.w;
            ssql += t0 * t0 + t1 * t1 + t2 * t2 + t3 * t3;
        }
        #pragma unroll
        for (int off = 32; off > 0; off >>= 1) ssql += __shfl_down(ssql, off);
        if ((tid & 63) == 0) ws[tid >> 6] = ssql;
        __syncthreads();
        if (tid == 0) {
            float s = 0.f;
            #pragma unroll
            for (int i = 0; i < 8; ++i) s += ws[i];
            atomicAdd(ssqp, s);
        }
    }
}

// -------------------------------------------------------------------
// exact fp32 re-argmin for triple-ambiguous tokens (latency-optimized:
// 1 token/block-pass, c0 unrolled 4x with loads up front, e2 in LDS,
// grid 2048). NEW: when the code changes, patch outq row + Delta-ssq
// (argmin wrote i1's row/ssq; formula q = x + (e-x) kept identical).
__launch_bounds__(256)
__global__ void k_fix(const float* __restrict__ x, const float* __restrict__ Et,
                      const float* __restrict__ e2, const int* __restrict__ rcnt,
                      const int* __restrict__ rlist, int* __restrict__ code_i,
                      float* __restrict__ code_f, int* __restrict__ cnt,
                      float* __restrict__ outq, float* __restrict__ ssqp) {
    __shared__ float4 xs[32];
    __shared__ float  e2s[K_];
    __shared__ float  sd[8];
    __shared__ int    si[8];
    __shared__ int    sfi, sob, schg;
    __shared__ float  wsf[4];
    int tid = threadIdx.x;
    int lane = tid & 63, w = tid >> 6;
    int half = lane >> 5;
    int q32  = lane & 31;
    int slot = w * 2 + half;     // 0..7: codes c ≡ slot (mod 8)
    int nr = *rcnt;
    for (int i = tid; i < K_; i += 256) e2s[i] = e2[i];

    for (int it = blockIdx.x; it < nr; it += gridDim.x) {
        __syncthreads();                      // e2s ready / prev iter done
        int tok = rlist[it];
        if (tid < 32) xs[tid] = ((const float4*)(x + (size_t)tok * D_))[tid];
        __syncthreads();
        float4 xv = xs[q32];
        float bd = INFINITY; int bb = 0;
        for (int c0 = 0; c0 < K_; c0 += 32) {
            int ca = c0 + slot, cb = ca + 8, cc = ca + 16, cd = ca + 24;
            float4 ea = ((const float4*)(Et + (size_t)ca * D_))[q32];
            float4 eb = ((const float4*)(Et + (size_t)cb * D_))[q32];
            float4 ec = ((const float4*)(Et + (size_t)cc * D_))[q32];
            float4 ed = ((const float4*)(Et + (size_t)cd * D_))[q32];
            float da = xv.x * ea.x + xv.y * ea.y + xv.z * ea.z + xv.w * ea.w;
            float db = xv.x * eb.x + xv.y * eb.y + xv.z * eb.z + xv.w * eb.w;
            float dc = xv.x * ec.x + xv.y * ec.y + xv.z * ec.z + xv.w * ec.w;
            float dd = xv.x * ed.x + xv.y * ed.y + xv.z * ed.z + xv.w * ed.w;
            #pragma unroll
            for (int m = 1; m <= 16; m <<= 1) {
                da += __shfl_xor(da, m);
                db += __shfl_xor(db, m);
                dc += __shfl_xor(dc, m);
                dd += __shfl_xor(dd, m);
            }
            float A = e2s[ca] - 2.f * da;
            float B = e2s[cb] - 2.f * db;
            float C = e2s[cc] - 2.f * dc;
            float Dv = e2s[cd] - 2.f * dd;
            if (A  < bd) { bd = A;  bb = ca; }
            if (B  < bd) { bd = B;  bb = cb; }
            if (C  < bd) { bd = C;  bb = cc; }
            if (Dv < bd) { bd = Dv; bb = cd; }
        }
        if (q32 == 0) { sd[slot] = bd; si[slot] = bb; }
        __syncthreads();
        if (tid == 0) {
            float fb = sd[0]; int fi = si[0];
            #pragma unroll
            for (int s = 1; s < 8; ++s) {
                if (sd[s] < fb || (sd[s] == fb && si[s] < fi)) { fb = sd[s]; fi = si[s]; }
            }
            int ob = code_i[tok];
            sfi = fi; sob = ob; schg = (fi != ob);
            if (fi != ob) {
                code_i[tok] = fi;
                code_f[tok] = (float)fi;
                atomicAdd(cnt + ob, -1);
                atomicAdd(cnt + fi, 1);
            }
        }
        __syncthreads();
        if (schg) {
            // patch the straight-through row + ssq delta
            float dl = 0.f;
            if (tid < 128) {
                float xd = ((const float*)xs)[tid];
                float eo = Et[(size_t)sob * D_ + tid];
                float en = Et[(size_t)sfi * D_ + tid];
                float qo = xd + (eo - xd);
                float qn = xd + (en - xd);
                outq[(size_t)tok * D_ + tid] = qn;
                float to_ = qo - xd, tn_ = qn - xd;
                dl = tn_ * tn_ - to_ * to_;
            }
            #pragma unroll
            for (int off = 32; off > 0; off >>= 1) dl += __shfl_down(dl, off);
            if ((tid & 63) == 0) wsf[tid >> 6] = dl;
            __syncthreads();
            if (tid == 0) atomicAdd(ssqp, (wsf[0] + wsf[1]) + (wsf[2] + wsf[3]));
        }
    }
}

// -------------------------------------------------------------------
// Fused scan+scatter: each block redundantly computes the exclusive
// scan of cnt[1024] in LDS, then scatters its 256 tokens via
// base[c] + atomicAdd(zc+c,1).
__launch_bounds__(256)
__global__ void k_scatter(const int* __restrict__ cnt, const int* __restrict__ code_i,
                          int* __restrict__ zc, int* __restrict__ order,
                          int* __restrict__ csort) {
    __shared__ int sbase[1024];
    __shared__ int wtot[4];
    int t = threadIdx.x;
    int lane = t & 63, wv = t >> 6;
    int c4[4];
    #pragma unroll
    for (int j = 0; j < 4; ++j) c4[j] = cnt[4 * t + j];
    int s = c4[0] + c4[1] + c4[2] + c4[3];
    int ps = s;
    #pragma unroll
    for (int m = 1; m < 64; m <<= 1) {
        int o = __shfl_up(ps, m);
        if (lane >= m) ps += o;
    }
    if (lane == 63) wtot[wv] = ps;
    __syncthreads();
    int woff = 0;
    for (int i = 0; i < 4; ++i) if (i < wv) woff += wtot[i];
    int run = woff + ps - s;
    #pragma unroll
    for (int j = 0; j < 4; ++j) {
        sbase[4 * t + j] = run;    // exclusive base of code 4t+j
        run += c4[j];
    }
    __syncthreads();

    int n = blockIdx.x * 256 + t;
    int c = code_i[n];
    int pos = sbase[c] + atomicAdd(zc + c, 1);
    order[pos] = n;
    csort[pos] = c;
}

// -------------------------------------------------------------------
// PURE segment-sum (dequant/ssq migrated into k_argmin/k_fix): block i
// owns sorted slots [32i,32i+32) as TWO independent 16-slot halves,
// each with its own running-sum flush chain into part1[c][d].
__launch_bounds__(256)
__global__ void k_segsum(const float* __restrict__ x, const int* __restrict__ order,
                         const int* __restrict__ csort, float* __restrict__ part1) {
    __shared__ int sn[WSEG], sc[WSEG];
    int tid = threadIdx.x;
    int d = tid & 127;
    int h = tid >> 7;                       // half 0/1
    int i0 = blockIdx.x * WSEG;
    if (tid < WSEG) { sn[tid] = order[i0 + tid]; sc[tid] = csort[i0 + tid]; }
    __syncthreads();
    int s0 = h * 16;
    int cprev = sc[s0];
    float acc = 0.f;
    float xv = x[(size_t)sn[s0] * D_ + d];
    #pragma unroll 4
    for (int j = 0; j < 16; ++j) {
        int sj = s0 + j;
        float xn = (j < 15) ? x[(size_t)sn[sj + 1] * D_ + d] : 0.f;  // prefetch
        int c = sc[sj];
        if (c != cprev) {                      // wave-uniform branch
            atomicAdd(&part1[(size_t)cprev * D_ + d], acc);
            acc = 0.f;
            cprev = c;
        }
        acc += xv;
        xv = xn;
    }
    atomicAdd(&part1[(size_t)cprev * D_ + d], acc);
}

// -------------------------------------------------------------------
// fused stats + embed: each block redundantly reduces n; block 0 also
// writes out_ncs + out_diff. Then EMA mean + divide for its 256 elems.
__launch_bounds__(256)
__global__ void k_embed(const float* __restrict__ em, const float* __restrict__ part1,
                        const int* __restrict__ cnt, const float* __restrict__ csz,
                        const float* __restrict__ ssqp, float* __restrict__ out_nmean,
                        float* __restrict__ out_nemb, float* __restrict__ out_ncs,
                        float* __restrict__ out_diff) {
    int tid = threadIdx.x;
    __shared__ float red[256];

    // ---- n = sum_k ncs_k (redundant per block) ----
    float ls = 0.f;
    for (int j = tid; j < K_; j += 256) ls += csz[j] * DECAY_ + OMD_ * (float)cnt[j];
    red[tid] = ls;
    __syncthreads();
    for (int off = 128; off > 0; off >>= 1) {
        if (tid < off) red[tid] += red[tid + off];
        __syncthreads();
    }
    float n = red[0];
    __syncthreads();

    if (blockIdx.x == 0) {
        for (int j = tid; j < K_; j += 256)
            out_ncs[j] = csz[j] * DECAY_ + OMD_ * (float)cnt[j];
        if (tid == 0) *out_diff = VQC_ * ssqp[0] / (float)(N_ * D_);
    }

    int i = blockIdx.x * 256 + tid;           // over D*K, layout [D][K]
    int k = i & (K_ - 1);
    int d = i >> 10;
    float ncs_k = csz[k] * DECAY_ + OMD_ * (float)cnt[k];
    float csk = (ncs_k + EPS_) / (n + (float)K_ * EPS_) * n;
    float es = part1[(size_t)k * D_ + d];
    float nm = em[i] * DECAY_ + OMD_ * es;
    out_nmean[i] = nm;
    out_nemb[i]  = nm / csk;
}

// -------------------------------------------------------------------
extern "C" void kernel_launch(void* const* d_in, const int* in_sizes, int n_in,
                              void* d_out, int out_size, void* d_ws, size_t ws_size,
                              hipStream_t stream) {
    const float* x   = (const float*)d_in[0];   // [16,4096,128]
    const float* E   = (const float*)d_in[1];   // [128,1024]
    const float* csz = (const float*)d_in[2];   // [1024]
    const float* em  = (const float*)d_in[3];   // [128,1024]
    float* out = (float*)d_out;
    float* W   = (float*)d_ws;

    int*   code_i = (int*)(W + WOFF_CODE);
    float* e2     = W + WOFF_E2;
    int*   cnt    = (int*)(W + WOFF_CNT);
    float* ssqp   = W + WOFF_SSQ;
    int*   rcnt   = (int*)(W + WOFF_RCNT);
    int*   zc     = (int*)(W + WOFF_CURS);
    int*   order  = (int*)(W + WOFF_ORDER);
    float* Et     = W + WOFF_ET;
    float* part1  = W + WOFF_PART;
    int*   csort  = (int*)(W + WOFF_CSORT);
    int*   rlist  = (int*)(W + WOFF_RLIST);
    unsigned short* Ef = (unsigned short*)(W + WOFF_EF);

    k_prep<<<64, 256, 0, stream>>>(E, Et, Ef, e2, cnt, zc, part1);
    k_argmin_mfma<<<N_ / 128, 512, 0, stream>>>(x, Ef, e2, code_i,
                                                out + OOFF_CODE, cnt, rcnt, rlist, Et,
                                                out + OOFF_Q, ssqp);
    k_fix<<<2048, 256, 0, stream>>>(x, Et, e2, rcnt, rlist, code_i, out + OOFF_CODE,
                                    cnt, out + OOFF_Q, ssqp);
    k_scatter<<<N_ / 256, 256, 0, stream>>>(cnt, code_i, zc, order, csort);
    k_segsum<<<N_ / WSEG, 256, 0, stream>>>(x, order, csort, part1);
    k_embed<<<(D_ * K_) / 256, 256, 0, stream>>>(em, part1, cnt, csz, ssqp,
                                                 out + OOFF_NMEAN, out + OOFF_NEMB,
                                                 out + OOFF_NCS, out + OOFF_DIFF);
}

// Round 18
// 206.713 us; speedup vs baseline: 1.3253x; 1.0167x over previous
//
#include <hip/hip_runtime.h>
#include <hip/hip_fp16.h>
#include <math.h>

#define D_ 128
#define K_ 1024
#define N_ 65536
#define DECAY_ 0.99f
#define OMD_ 0.01f
#define EPS_ 1e-5f
#define VQC_ 0.25f
#define M1_ 0.14f     // pair band: 2*eps(fp16 dot) + 2*keytrunc
#define M2_ 0.14f     // triple band -> full K rescan
#define BIAS_ 96.0f   // positivity shift for e2-2xe (argmin-invariant per token)
#define CLMIN_ 0.5f
#define CLMAX_ 508.0f // keys < 512 => trunc ULP 2^-5; clamped => triple-flagged
#define WSEG 32       // tokens per k_segsum block (2 x 16-slot halves)

typedef __attribute__((ext_vector_type(8))) _Float16 half8;
typedef __attribute__((ext_vector_type(4))) float f32x4;

// ---- workspace offsets (in 4-byte elements) ----
#define WOFF_CODE  0          // int[65536]
#define WOFF_E2    65536      // float[1024]
#define WOFF_CNT   66560      // int[1024]
#define WOFF_SSQ   67584      // float[1]  (zeroed by k_prep block 0)
#define WOFF_RCNT  67585      // int[1]    (CNT..RCNT zeroed by k_prep block 0)
#define WOFF_BASE  67648      // int[1025] (unused; scan fused into k_scatter)
#define WOFF_CURS  68736      // int[1024] zero-based scatter cursor (zeroed by prep)
#define WOFF_ORDER 69760      // int[65536]
#define WOFF_ET    136320     // float[131072] (K x D), 16B aligned
#define WOFF_PART  267392     // float[131072] (K x D) atomic segment sums
#define WOFF_CSORT 398464     // int[65536] code of each sorted slot
#define WOFF_RLIST 791680     // int[65536]
#define WOFF_EF    857216     // ushort[131072] frag-ordered fp16 of -2E

// ---- output offsets (in floats), reference return order ----
#define OOFF_Q     0          // [16,4096,128]
#define OOFF_DIFF  8388608    // scalar
#define OOFF_CODE  8388609    // [16,4096]
#define OOFF_NEMB  8454145    // [128,1024]
#define OOFF_NCS   8585217    // [1024]
#define OOFF_NMEAN 8586241    // [128,1024]

__device__ __forceinline__ unsigned umin32(unsigned a, unsigned b) { return a < b ? a : b; }
__device__ __forceinline__ unsigned umax32(unsigned a, unsigned b) { return a > b ? a : b; }

// async global->LDS 16B per lane (direct DMA, no VGPR round-trip)
__device__ __forceinline__ void gld16(const unsigned short* g, unsigned short* l) {
    __builtin_amdgcn_global_load_lds(
        (const __attribute__((address_space(1))) unsigned int*)g,
        (__attribute__((address_space(3))) unsigned int*)l, 16, 0, 0);
}

// -------------------------------------------------------------------
// Fused prep: E [D][K] -> Et [K][D], fp16 frag plane Ef of -2E, e2,
// cnt/ssq/rcnt zeroing (block 0), zc zeroing (block 1), part1 zeroing.
__launch_bounds__(256)
__global__ void k_prep(const float* __restrict__ E, float* __restrict__ Et,
                       unsigned short* __restrict__ Ef, float* __restrict__ e2,
                       int* __restrict__ cnt, int* __restrict__ zc,
                       float* __restrict__ part1) {
    __shared__ float tile[128 * 17];   // tile[d][cc], pad 17 vs 16
    __shared__ float e2s[16];
    int tid = threadIdx.x;
    int b = blockIdx.x;                // 0..63
    int c0 = b * 16;
    if (b == 0) {
        for (int i = tid; i < 1026; i += 256) cnt[i] = 0;   // cnt[1024], ssq, rcnt
    }
    if (b == 1) {
        for (int i = tid; i < 1024; i += 256) zc[i] = 0;    // scatter cursor
    }
    // zero part1 (K*D floats, 2048 per block)
    #pragma unroll
    for (int i = 0; i < 8; ++i) part1[b * 2048 + i * 256 + tid] = 0.f;
    if (tid < 16) e2s[tid] = 0.f;
    // ---- load E columns c0..c0+15 (2048 floats) ----
    #pragma unroll
    for (int i = 0; i < 8; ++i) {
        int idx = i * 256 + tid;       // 0..2047
        int d = idx >> 4, cc = idx & 15;
        tile[d * 17 + cc] = E[d * K_ + c0 + cc];
    }
    __syncthreads();
    // ---- write Et rows (coalesced, conflict-free via pad) ----
    #pragma unroll
    for (int i = 0; i < 8; ++i) {
        int idx = i * 256 + tid;
        int cc = idx >> 7, d = idx & 127;
        Et[(size_t)(c0 + cc) * D_ + d] = tile[d * 17 + cc];
    }
    // ---- Ef frags + e2 ----
    int L = tid & 63, s = tid >> 6;
    int cc = L & 15;
    int d0 = s * 32 + ((L >> 4) << 3);
    unsigned short h[8];
    float sq = 0.f;
    #pragma unroll
    for (int j = 0; j < 8; ++j) {
        float e = tile[(d0 + j) * 17 + cc];
        sq = fmaf(e, e, sq);
        h[j] = __half_as_ushort(__float2half(-2.f * e));
    }
    int T = b * 256 + tid;
    #pragma unroll
    for (int j = 0; j < 8; ++j) Ef[T * 8 + j] = h[j];
    atomicAdd(&e2s[cc], sq);
    __syncthreads();
    if (tid < 16) {
        e2[c0 + tid] = e2s[tid];
    }
}

// -------------------------------------------------------------------
// MFMA argmin — measured-best R4/R15 configuration (55.3-55.9us across
// four independent benches): 3-buffer LDS ring (52 KB), stage-AFTER-
// compute into slot (q+2)%3 (WAR-safe), counted vmcnt(2) keeps the NEXT
// chunk's DMA in flight across every barrier. Bound (512,4): VGPR 64.
// Dequant is NOT fused here: R16 measured +15us for the epilogue ride-
// along (x evicted from L2 by the Ef stream -> +14.5MB HBM re-fetch,
// +32MB write at the kernel tail). Dequant lives in k_scatter now
// (sequential order, post-k_fix).
__launch_bounds__(512, 4)
__global__ void k_argmin_mfma(const float* __restrict__ x, const unsigned short* __restrict__ Ef,
                              const float* __restrict__ e2,
                              int* __restrict__ code_i, float* __restrict__ code_f,
                              int* __restrict__ cnt, int* __restrict__ rcnt,
                              int* __restrict__ rlist, const float* __restrict__ Et) {
    __shared__ unsigned short Bs[3][8192];   // 3 x 16 KB chunk ring
    __shared__ float e2s[K_];
    int tid = threadIdx.x;
    int w = tid >> 6, L = tid & 63, quad = L >> 4, col = L & 15;
    int mg = w >> 1, ng = w & 1;             // mg 0..3 (32-token groups), ng 0..1 (code half)
    int n0 = blockIdx.x * 128;

    for (int i = tid; i < K_; i += 512) e2s[i] = e2[i];

    // ---- A fragments (32 tokens/wave, fp16) ----
    half8 ah[2][4];
    #pragma unroll
    for (int mt = 0; mt < 2; ++mt) {
        int tok = n0 + (2 * mg + mt) * 16 + col;
        #pragma unroll
        for (int s = 0; s < 4; ++s) {
            const float* p = x + (size_t)tok * D_ + s * 32 + quad * 8;
            float4 u0 = *(const float4*)(p);
            float4 u1 = *(const float4*)(p + 4);
            ah[mt][s][0] = (_Float16)u0.x; ah[mt][s][1] = (_Float16)u0.y;
            ah[mt][s][2] = (_Float16)u0.z; ah[mt][s][3] = (_Float16)u0.w;
            ah[mt][s][4] = (_Float16)u1.x; ah[mt][s][5] = (_Float16)u1.y;
            ah[mt][s][6] = (_Float16)u1.z; ah[mt][s][7] = (_Float16)u1.w;
        }
    }

    unsigned k1[2][4], k2[2][4], k3[2][4];
    #pragma unroll
    for (int mt = 0; mt < 2; ++mt)
        #pragma unroll
        for (int r = 0; r < 4; ++r) {
            k1[mt][r] = 0xFFFFFFFFu; k2[mt][r] = 0xFFFFFFFFu; k3[mt][r] = 0xFFFFFFFFu;
        }

    __syncthreads();                          // e2s visible; nothing else in flight

    // ---- prologue: stage chunks 0,1 into slots 0,1 (2 ops each/wave) ----
    #pragma unroll
    for (int i = 0; i < 2; ++i) {
        int o = (w * 2 + i) * 512;
        gld16(Ef + o + L * 8, &Bs[0][o]);
    }
    #pragma unroll
    for (int i = 0; i < 2; ++i) {
        int o = (w * 2 + i) * 512;
        gld16(Ef + 8192 + o + L * 8, &Bs[1][o]);
    }

    #pragma unroll
    for (int q = 0; q < 16; ++q) {
        // outstanding here: chunk q (2 ops) + chunk q+1 (2 ops).
        // vmcnt(2) retires MY chunk-q loads; barrier => ALL waves' retired.
        if (q < 15) asm volatile("s_waitcnt vmcnt(2)" ::: "memory");
        else        asm volatile("s_waitcnt vmcnt(0)" ::: "memory");
        __builtin_amdgcn_s_barrier();
        asm volatile("" ::: "memory");

        const unsigned short* Bp = &Bs[q % 3][0];

        // ---- acc init = e2[code] + BIAS ----
        float evb[2];
        #pragma unroll
        for (int nn = 0; nn < 2; ++nn)
            evb[nn] = e2s[q * 64 + (2 * ng + nn) * 16 + col] + BIAS_;
        f32x4 acc[2][2];
        #pragma unroll
        for (int mt = 0; mt < 2; ++mt)
            #pragma unroll
            for (int nn = 0; nn < 2; ++nn)
                #pragma unroll
                for (int r = 0; r < 4; ++r)
                    acc[mt][nn][r] = evb[nn];

        // ---- 16 MFMA: 4 k-steps x 2 n-subs x 2 m-tiles ----
        #pragma unroll
        for (int s = 0; s < 4; ++s) {
            half8 bh[2];
            #pragma unroll
            for (int nn = 0; nn < 2; ++nn) {
                int off = (((2 * ng + nn) * 4 + s) * 64 + L) * 8;
                bh[nn] = *(const half8*)(Bp + off);
            }
            #pragma unroll
            for (int nn = 0; nn < 2; ++nn)
                #pragma unroll
                for (int mt = 0; mt < 2; ++mt)
                    acc[mt][nn] = __builtin_amdgcn_mfma_f32_16x16x32_f16(ah[mt][s], bh[nn], acc[mt][nn], 0, 0, 0);
        }

        // ---- clamp to [0.5,508] + packed-key top-3 insert ----
        #pragma unroll
        for (int nn = 0; nn < 2; ++nn) {
            unsigned cb = (unsigned)(q * 64 + (2 * ng + nn) * 16 + col);
            #pragma unroll
            for (int mt = 0; mt < 2; ++mt)
                #pragma unroll
                for (int r = 0; r < 4; ++r) {
                    float dc = fminf(fmaxf(acc[mt][nn][r], CLMIN_), CLMAX_);
                    unsigned key = (__float_as_uint(dc) & 0xFFFFFC00u) | cb;
                    unsigned m1 = umax32(k1[mt][r], key);
                    k1[mt][r]   = umin32(k1[mt][r], key);
                    unsigned m2 = umax32(k2[mt][r], m1);
                    k2[mt][r]   = umin32(k2[mt][r], m1);
                    k3[mt][r]   = umin32(k3[mt][r], m2);
                }
        }

        // ---- stage chunk q+2 into slot (q+2)%3 (WAR-safe) ----
        if (q < 14) {
            const unsigned short* src = Ef + (q + 2) * 8192;
            int sl = (q + 2) % 3;
            #pragma unroll
            for (int i = 0; i < 2; ++i) {
                int o = (w * 2 + i) * 512;
                gld16(src + o + L * 8, &Bs[sl][o]);
            }
        }
    }

    // ---- cross-lane merge of sorted triples over 16 cols ----
    __syncthreads();
    unsigned* mk1 = (unsigned*)&Bs[0][0];     // [128 tokens][2 halves] x 3
    unsigned* mk2 = mk1 + 256;
    unsigned* mk3 = mk2 + 256;

    #pragma unroll
    for (int mt = 0; mt < 2; ++mt) {
        #pragma unroll
        for (int r = 0; r < 4; ++r) {
            unsigned a = k1[mt][r], b = k2[mt][r], c = k3[mt][r];
            #pragma unroll
            for (int m = 1; m < 16; m <<= 1) {
                unsigned ao = (unsigned)__shfl_xor((int)a, m);
                unsigned bo = (unsigned)__shfl_xor((int)b, m);
                unsigned co = (unsigned)__shfl_xor((int)c, m);
                unsigned t1 = umax32(a, ao);
                a           = umin32(a, ao);
                unsigned s2 = umin32(b, bo);
                unsigned u  = umax32(t1, s2);
                b           = umin32(t1, s2);
                c           = umin32(u, umin32(c, co));
            }
            if (col == 0) {
                int tl = (2 * mg + mt) * 16 + quad * 4 + r;
                mk1[tl * 2 + ng] = a;
                mk2[tl * 2 + ng] = b;
                mk3[tl * 2 + ng] = c;
            }
        }
    }
    __syncthreads();
    if (tid < 128) {
        unsigned a1 = mk1[tid * 2], b1 = mk1[tid * 2 + 1];
        unsigned a2 = mk2[tid * 2], b2 = mk2[tid * 2 + 1];
        unsigned a3 = mk3[tid * 2], b3 = mk3[tid * 2 + 1];
        unsigned t1 = umax32(a1, b1);
        unsigned kk1 = umin32(a1, b1);
        unsigned s2 = umin32(a2, b2);
        unsigned kk2 = umin32(t1, s2);
        unsigned u  = umax32(t1, s2);
        unsigned kk3 = umin32(u, umin32(a3, b3));

        int i1 = (int)(kk1 & 1023u), i2 = (int)(kk2 & 1023u);
        float d1 = __uint_as_float(kk1 & 0xFFFFFC00u);
        float d2 = __uint_as_float(kk2 & 0xFFFFFC00u);
        float d3 = __uint_as_float(kk3 & 0xFFFFFC00u);
        int tok = n0 + tid;

        if (d3 - d1 < M2_) {
            // 3+ codes inside the uncertainty band: full exact rescan later
            code_i[tok] = i1;
            code_f[tok] = (float)i1;
            atomicAdd(cnt + i1, 1);
            int p = atomicAdd(rcnt, 1);
            rlist[p] = tok;
        } else {
            int win = i1;
            if (d2 - d1 < M1_) {
                // exact fp32 pair decision, inline (true argmin is i1 or i2)
                const float* xr = x  + (size_t)tok * D_;
                const float* ea = Et + (size_t)i1 * D_;
                const float* eb = Et + (size_t)i2 * D_;
                float s1 = 0.f, sB = 0.f;
                #pragma unroll 4
                for (int dd = 0; dd < D_; dd += 4) {
                    float4 xv = *(const float4*)(xr + dd);
                    float4 av = *(const float4*)(ea + dd);
                    float4 bv = *(const float4*)(eb + dd);
                    s1 = fmaf(xv.x, av.x, s1); s1 = fmaf(xv.y, av.y, s1);
                    s1 = fmaf(xv.z, av.z, s1); s1 = fmaf(xv.w, av.w, s1);
                    sB = fmaf(xv.x, bv.x, sB); sB = fmaf(xv.y, bv.y, sB);
                    sB = fmaf(xv.z, bv.z, sB); sB = fmaf(xv.w, bv.w, sB);
                }
                float ex1 = e2s[i1] - 2.f * s1;
                float ex2 = e2s[i2] - 2.f * sB;
                if (ex2 < ex1 || (ex2 == ex1 && i2 < i1)) win = i2;
            }
            code_i[tok] = win;
            code_f[tok] = (float)win;
            atomicAdd(cnt + win, 1);
        }
    }
}

// -------------------------------------------------------------------
// exact fp32 re-argmin for triple-ambiguous tokens (latency-optimized:
// 1 token/block-pass, c0 unrolled 4x with loads up front, e2 in LDS,
// grid 2048). No outq patch — dequant runs after k_fix in k_scatter.
__launch_bounds__(256)
__global__ void k_fix(const float* __restrict__ x, const float* __restrict__ Et,
                      const float* __restrict__ e2, const int* __restrict__ rcnt,
                      const int* __restrict__ rlist, int* __restrict__ code_i,
                      float* __restrict__ code_f, int* __restrict__ cnt) {
    __shared__ float4 xs[32];
    __shared__ float  e2s[K_];
    __shared__ float  sd[8];
    __shared__ int    si[8];
    int tid = threadIdx.x;
    int lane = tid & 63, w = tid >> 6;
    int half = lane >> 5;
    int q32  = lane & 31;
    int slot = w * 2 + half;     // 0..7: codes c ≡ slot (mod 8)
    int nr = *rcnt;
    for (int i = tid; i < K_; i += 256) e2s[i] = e2[i];

    for (int it = blockIdx.x; it < nr; it += gridDim.x) {
        __syncthreads();                      // e2s ready / prev iter merged
        int tok = rlist[it];
        if (tid < 32) xs[tid] = ((const float4*)(x + (size_t)tok * D_))[tid];
        __syncthreads();
        float4 xv = xs[q32];
        float bd = INFINITY; int bb = 0;
        for (int c0 = 0; c0 < K_; c0 += 32) {
            int ca = c0 + slot, cb = ca + 8, cc = ca + 16, cd = ca + 24;
            // 4 independent Et loads issued up front (break load-use chain)
            float4 ea = ((const float4*)(Et + (size_t)ca * D_))[q32];
            float4 eb = ((const float4*)(Et + (size_t)cb * D_))[q32];
            float4 ec = ((const float4*)(Et + (size_t)cc * D_))[q32];
            float4 ed = ((const float4*)(Et + (size_t)cd * D_))[q32];
            float da = xv.x * ea.x + xv.y * ea.y + xv.z * ea.z + xv.w * ea.w;
            float db = xv.x * eb.x + xv.y * eb.y + xv.z * eb.z + xv.w * eb.w;
            float dc = xv.x * ec.x + xv.y * ec.y + xv.z * ec.z + xv.w * ec.w;
            float dd = xv.x * ed.x + xv.y * ed.y + xv.z * ed.z + xv.w * ed.w;
            #pragma unroll
            for (int m = 1; m <= 16; m <<= 1) {   // 4 interleaved reduce chains
                da += __shfl_xor(da, m);
                db += __shfl_xor(db, m);
                dc += __shfl_xor(dc, m);
                dd += __shfl_xor(dd, m);
            }
            float A = e2s[ca] - 2.f * da;
            float B = e2s[cb] - 2.f * db;
            float C = e2s[cc] - 2.f * dc;
            float Dv = e2s[cd] - 2.f * dd;
            if (A  < bd) { bd = A;  bb = ca; }   // ascending code order =>
            if (B  < bd) { bd = B;  bb = cb; }   // strict < keeps first-min
            if (C  < bd) { bd = C;  bb = cc; }
            if (Dv < bd) { bd = Dv; bb = cd; }
        }
        if (q32 == 0) { sd[slot] = bd; si[slot] = bb; }
        __syncthreads();
        if (tid == 0) {
            float fb = sd[0]; int fi = si[0];
            #pragma unroll
            for (int s = 1; s < 8; ++s) {
                if (sd[s] < fb || (sd[s] == fb && si[s] < fi)) { fb = sd[s]; fi = si[s]; }
            }
            int ob = code_i[tok];
            if (fi != ob) {
                code_i[tok] = fi;
                code_f[tok] = (float)fi;
                atomicAdd(cnt + ob, -1);
                atomicAdd(cnt + fi, 1);
            }
        }
    }
}

// -------------------------------------------------------------------
// Fused scan + scatter + DEQUANT/ST/ssq: runs after k_fix so codes are
// final. Phase 1: per-block redundant exclusive scan of cnt (LDS) +
// scatter of this block's 256 tokens (codes buffered in LDS).
// Phase 2: sequential-order dequant — 8 passes x 32 tokens, 8 threads
// per token x 16 dims (wave covers 4KB contiguous: coalesced x read +
// outq write; Et rows are L2-resident) + ssq block-reduce -> 1 atomic.
// Sequential order beats both prior homes: segdeq's sorted-random rows
// (~27us) and argmin's epilogue after L2 eviction (+15us).
__launch_bounds__(256)
__global__ void k_scatter(const int* __restrict__ cnt, const int* __restrict__ code_i,
                          int* __restrict__ zc, int* __restrict__ order,
                          int* __restrict__ csort, const float* __restrict__ x,
                          const float* __restrict__ Et, float* __restrict__ outq,
                          float* __restrict__ ssqp) {
    __shared__ int sbase[1024];
    __shared__ int wtot[4];
    __shared__ int scode[256];
    __shared__ float wsf[4];
    int t = threadIdx.x;
    int lane = t & 63, wv = t >> 6;
    int c4[4];
    #pragma unroll
    for (int j = 0; j < 4; ++j) c4[j] = cnt[4 * t + j];
    int s = c4[0] + c4[1] + c4[2] + c4[3];
    int ps = s;
    #pragma unroll
    for (int m = 1; m < 64; m <<= 1) {
        int o = __shfl_up(ps, m);
        if (lane >= m) ps += o;
    }
    if (lane == 63) wtot[wv] = ps;
    __syncthreads();
    int woff = 0;
    for (int i = 0; i < 4; ++i) if (i < wv) woff += wtot[i];
    int run = woff + ps - s;
    #pragma unroll
    for (int j = 0; j < 4; ++j) {
        sbase[4 * t + j] = run;    // exclusive base of code 4t+j
        run += c4[j];
    }
    __syncthreads();

    int n = blockIdx.x * 256 + t;
    int c = code_i[n];
    scode[t] = c;
    int pos = sbase[c] + atomicAdd(zc + c, 1);
    order[pos] = n;
    csort[pos] = c;
    __syncthreads();

    // ---- phase 2: dequant/ST + ssq, sequential token order ----
    int tk8 = t >> 3;               // 0..31: token within pass
    int db  = (t & 7) * 16;         // dim base (4 x float4)
    float ssql = 0.f;
    #pragma unroll
    for (int pass = 0; pass < 8; ++pass) {
        int li  = pass * 32 + tk8;  // token slot in block
        int tok = blockIdx.x * 256 + li;
        int cc  = scode[li];
        const float* xr = x    + (size_t)tok * D_ + db;
        const float* er = Et   + (size_t)cc  * D_ + db;
        float*       qr = outq + (size_t)tok * D_ + db;
        #pragma unroll
        for (int k2 = 0; k2 < 4; ++k2) {
            float4 xv = *(const float4*)(xr + k2 * 4);
            float4 ev = *(const float4*)(er + k2 * 4);
            float4 qv;
            qv.x = xv.x + (ev.x - xv.x);      // reference fp32 rounding
            qv.y = xv.y + (ev.y - xv.y);
            qv.z = xv.z + (ev.z - xv.z);
            qv.w = xv.w + (ev.w - xv.w);
            *(float4*)(qr + k2 * 4) = qv;
            float t0 = qv.x - xv.x, t1 = qv.y - xv.y;
            float t2 = qv.z - xv.z, t3 = qv.w - xv.w;
            ssql += t0 * t0 + t1 * t1 + t2 * t2 + t3 * t3;
        }
    }
    #pragma unroll
    for (int off = 32; off > 0; off >>= 1) ssql += __shfl_down(ssql, off);
    if ((t & 63) == 0) wsf[t >> 6] = ssql;
    __syncthreads();
    if (t == 0) atomicAdd(ssqp, (wsf[0] + wsf[1]) + (wsf[2] + wsf[3]));
}

// -------------------------------------------------------------------
// PURE segment-sum: block i owns sorted slots [32i,32i+32) as TWO
// independent 16-slot halves, each with its own running-sum flush
// chain into part1[c][d].
__launch_bounds__(256)
__global__ void k_segsum(const float* __restrict__ x, const int* __restrict__ order,
                         const int* __restrict__ csort, float* __restrict__ part1) {
    __shared__ int sn[WSEG], sc[WSEG];
    int tid = threadIdx.x;
    int d = tid & 127;
    int h = tid >> 7;                       // half 0/1
    int i0 = blockIdx.x * WSEG;
    if (tid < WSEG) { sn[tid] = order[i0 + tid]; sc[tid] = csort[i0 + tid]; }
    __syncthreads();
    int s0 = h * 16;
    int cprev = sc[s0];
    float acc = 0.f;
    float xv = x[(size_t)sn[s0] * D_ + d];
    #pragma unroll 4
    for (int j = 0; j < 16; ++j) {
        int sj = s0 + j;
        float xn = (j < 15) ? x[(size_t)sn[sj + 1] * D_ + d] : 0.f;  // prefetch
        int c = sc[sj];
        if (c != cprev) {                      // wave-uniform branch
            atomicAdd(&part1[(size_t)cprev * D_ + d], acc);
            acc = 0.f;
            cprev = c;
        }
        acc += xv;
        xv = xn;
    }
    atomicAdd(&part1[(size_t)cprev * D_ + d], acc);
}

// -------------------------------------------------------------------
// fused stats + embed: each block redundantly reduces n; block 0 also
// writes out_ncs + out_diff. Then EMA mean + divide for its 256 elems.
__launch_bounds__(256)
__global__ void k_embed(const float* __restrict__ em, const float* __restrict__ part1,
                        const int* __restrict__ cnt, const float* __restrict__ csz,
                        const float* __restrict__ ssqp, float* __restrict__ out_nmean,
                        float* __restrict__ out_nemb, float* __restrict__ out_ncs,
                        float* __restrict__ out_diff) {
    int tid = threadIdx.x;
    __shared__ float red[256];

    // ---- n = sum_k ncs_k (redundant per block) ----
    float ls = 0.f;
    for (int j = tid; j < K_; j += 256) ls += csz[j] * DECAY_ + OMD_ * (float)cnt[j];
    red[tid] = ls;
    __syncthreads();
    for (int off = 128; off > 0; off >>= 1) {
        if (tid < off) red[tid] += red[tid + off];
        __syncthreads();
    }
    float n = red[0];
    __syncthreads();

    if (blockIdx.x == 0) {
        for (int j = tid; j < K_; j += 256)
            out_ncs[j] = csz[j] * DECAY_ + OMD_ * (float)cnt[j];
        if (tid == 0) *out_diff = VQC_ * ssqp[0] / (float)(N_ * D_);
    }

    int i = blockIdx.x * 256 + tid;           // over D*K, layout [D][K]
    int k = i & (K_ - 1);
    int d = i >> 10;
    float ncs_k = csz[k] * DECAY_ + OMD_ * (float)cnt[k];
    float csk = (ncs_k + EPS_) / (n + (float)K_ * EPS_) * n;
    float es = part1[(size_t)k * D_ + d];
    float nm = em[i] * DECAY_ + OMD_ * es;
    out_nmean[i] = nm;
    out_nemb[i]  = nm / csk;
}

// -------------------------------------------------------------------
extern "C" void kernel_launch(void* const* d_in, const int* in_sizes, int n_in,
                              void* d_out, int out_size, void* d_ws, size_t ws_size,
                              hipStream_t stream) {
    const float* x   = (const float*)d_in[0];   // [16,4096,128]
    const float* E   = (const float*)d_in[1];   // [128,1024]
    const float* csz = (const float*)d_in[2];   // [1024]
    const float* em  = (const float*)d_in[3];   // [128,1024]
    float* out = (float*)d_out;
    float* W   = (float*)d_ws;

    int*   code_i = (int*)(W + WOFF_CODE);
    float* e2     = W + WOFF_E2;
    int*   cnt    = (int*)(W + WOFF_CNT);
    float* ssqp   = W + WOFF_SSQ;
    int*   rcnt   = (int*)(W + WOFF_RCNT);
    int*   zc     = (int*)(W + WOFF_CURS);
    int*   order  = (int*)(W + WOFF_ORDER);
    float* Et     = W + WOFF_ET;
    float* part1  = W + WOFF_PART;
    int*   csort  = (int*)(W + WOFF_CSORT);
    int*   rlist  = (int*)(W + WOFF_RLIST);
    unsigned short* Ef = (unsigned short*)(W + WOFF_EF);

    k_prep<<<64, 256, 0, stream>>>(E, Et, Ef, e2, cnt, zc, part1);
    k_argmin_mfma<<<N_ / 128, 512, 0, stream>>>(x, Ef, e2, code_i,
                                                out + OOFF_CODE, cnt, rcnt, rlist, Et);
    k_fix<<<2048, 256, 0, stream>>>(x, Et, e2, rcnt, rlist, code_i, out + OOFF_CODE, cnt);
    k_scatter<<<N_ / 256, 256, 0, stream>>>(cnt, code_i, zc, order, csort,
                                            x, Et, out + OOFF_Q, ssqp);
    k_segsum<<<N_ / WSEG, 256, 0, stream>>>(x, order, csort, part1);
    k_embed<<<(D_ * K_) / 256, 256, 0, stream>>>(em, part1, cnt, csz, ssqp,
                                                 out + OOFF_NMEAN, out + OOFF_NEMB,
                                                 out + OOFF_NCS, out + OOFF_DIFF);
}

// Round 19
// 206.041 us; speedup vs baseline: 1.3296x; 1.0033x over previous
//
#include <hip/hip_runtime.h>
#include <hip/hip_fp16.h>
#include <math.h>

#define D_ 128
#define K_ 1024
#define N_ 65536
#define DECAY_ 0.99f
#define OMD_ 0.01f
#define EPS_ 1e-5f
#define VQC_ 0.25f
#define M1_ 0.14f     // pair band: 2*eps(fp16 dot) + 2*keytrunc
#define M2_ 0.14f     // triple band -> full K rescan
#define BIAS_ 96.0f   // positivity shift for e2-2xe (argmin-invariant per token)
#define CLMIN_ 0.5f
#define CLMAX_ 508.0f // keys < 512 => trunc ULP 2^-5; clamped => triple-flagged
#define WSEG 32       // tokens per k_segsum block (2 x 16-slot halves)

typedef __attribute__((ext_vector_type(8))) _Float16 half8;
typedef __attribute__((ext_vector_type(4))) float f32x4;

// ---- workspace offsets (in 4-byte elements) ----
#define WOFF_CODE  0          // int[65536]
#define WOFF_E2    65536      // float[1024]
#define WOFF_CNT   66560      // int[1024]
#define WOFF_SSQ   67584      // float[1]  (zeroed by k_prep block 0)
#define WOFF_RCNT  67585      // int[1]    (CNT..RCNT zeroed by k_prep block 0)
#define WOFF_BASE  67648      // int[1025] (unused; scan fused into k_scatter)
#define WOFF_CURS  68736      // int[1024] zero-based scatter cursor (zeroed by prep)
#define WOFF_ORDER 69760      // int[65536]
#define WOFF_ET    136320     // float[131072] (K x D), 16B aligned
#define WOFF_PART  267392     // float[131072] (K x D) atomic segment sums
#define WOFF_CSORT 398464     // int[65536] code of each sorted slot
#define WOFF_RLIST 791680     // int[65536]
#define WOFF_EF    857216     // ushort[131072] frag-ordered fp16 of -2E

// ---- output offsets (in floats), reference return order ----
#define OOFF_Q     0          // [16,4096,128]
#define OOFF_DIFF  8388608    // scalar
#define OOFF_CODE  8388609    // [16,4096]
#define OOFF_NEMB  8454145    // [128,1024]
#define OOFF_NCS   8585217    // [1024]
#define OOFF_NMEAN 8586241    // [128,1024]

__device__ __forceinline__ unsigned umin32(unsigned a, unsigned b) { return a < b ? a : b; }
__device__ __forceinline__ unsigned umax32(unsigned a, unsigned b) { return a > b ? a : b; }

// async global->LDS 16B per lane (direct DMA, no VGPR round-trip)
__device__ __forceinline__ void gld16(const unsigned short* g, unsigned short* l) {
    __builtin_amdgcn_global_load_lds(
        (const __attribute__((address_space(1))) unsigned int*)g,
        (__attribute__((address_space(3))) unsigned int*)l, 16, 0, 0);
}

// -------------------------------------------------------------------
// Fused prep: E [D][K] -> Et [K][D], fp16 frag plane Ef of -2E, e2,
// cnt/ssq/rcnt zeroing (block 0), zc zeroing (block 1), part1 zeroing.
__launch_bounds__(256)
__global__ void k_prep(const float* __restrict__ E, float* __restrict__ Et,
                       unsigned short* __restrict__ Ef, float* __restrict__ e2,
                       int* __restrict__ cnt, int* __restrict__ zc,
                       float* __restrict__ part1) {
    __shared__ float tile[128 * 17];   // tile[d][cc], pad 17 vs 16
    __shared__ float e2s[16];
    int tid = threadIdx.x;
    int b = blockIdx.x;                // 0..63
    int c0 = b * 16;
    if (b == 0) {
        for (int i = tid; i < 1026; i += 256) cnt[i] = 0;   // cnt[1024], ssq, rcnt
    }
    if (b == 1) {
        for (int i = tid; i < 1024; i += 256) zc[i] = 0;    // scatter cursor
    }
    // zero part1 (K*D floats, 2048 per block)
    #pragma unroll
    for (int i = 0; i < 8; ++i) part1[b * 2048 + i * 256 + tid] = 0.f;
    if (tid < 16) e2s[tid] = 0.f;
    // ---- load E columns c0..c0+15 (2048 floats) ----
    #pragma unroll
    for (int i = 0; i < 8; ++i) {
        int idx = i * 256 + tid;       // 0..2047
        int d = idx >> 4, cc = idx & 15;
        tile[d * 17 + cc] = E[d * K_ + c0 + cc];
    }
    __syncthreads();
    // ---- write Et rows (coalesced, conflict-free via pad) ----
    #pragma unroll
    for (int i = 0; i < 8; ++i) {
        int idx = i * 256 + tid;
        int cc = idx >> 7, d = idx & 127;
        Et[(size_t)(c0 + cc) * D_ + d] = tile[d * 17 + cc];
    }
    // ---- Ef frags + e2 ----
    int L = tid & 63, s = tid >> 6;
    int cc = L & 15;
    int d0 = s * 32 + ((L >> 4) << 3);
    unsigned short h[8];
    float sq = 0.f;
    #pragma unroll
    for (int j = 0; j < 8; ++j) {
        float e = tile[(d0 + j) * 17 + cc];
        sq = fmaf(e, e, sq);
        h[j] = __half_as_ushort(__float2half(-2.f * e));
    }
    int T = b * 256 + tid;
    #pragma unroll
    for (int j = 0; j < 8; ++j) Ef[T * 8 + j] = h[j];
    atomicAdd(&e2s[cc], sq);
    __syncthreads();
    if (tid < 16) {
        e2[c0 + tid] = e2s[tid];
    }
}

// -------------------------------------------------------------------
// MFMA argmin — measured-best R4/R15 configuration (55.3-57.2us across
// five independent benches): 3-buffer LDS ring (52 KB), stage-AFTER-
// compute into slot (q+2)%3 (WAR-safe), counted vmcnt(2) keeps the NEXT
// chunk's DMA in flight across every barrier. Bound (512,4): VGPR 64.
// Dequant lives in k_scatter (sequential order, post-k_fix): measured
// cheapest of three homes (segdeq ~27us, argmin-epilogue ~15us,
// scatter ~11us).
__launch_bounds__(512, 4)
__global__ void k_argmin_mfma(const float* __restrict__ x, const unsigned short* __restrict__ Ef,
                              const float* __restrict__ e2,
                              int* __restrict__ code_i, float* __restrict__ code_f,
                              int* __restrict__ cnt, int* __restrict__ rcnt,
                              int* __restrict__ rlist, const float* __restrict__ Et) {
    __shared__ unsigned short Bs[3][8192];   // 3 x 16 KB chunk ring
    __shared__ float e2s[K_];
    int tid = threadIdx.x;
    int w = tid >> 6, L = tid & 63, quad = L >> 4, col = L & 15;
    int mg = w >> 1, ng = w & 1;             // mg 0..3 (32-token groups), ng 0..1 (code half)
    int n0 = blockIdx.x * 128;

    for (int i = tid; i < K_; i += 512) e2s[i] = e2[i];

    // ---- A fragments (32 tokens/wave, fp16) ----
    half8 ah[2][4];
    #pragma unroll
    for (int mt = 0; mt < 2; ++mt) {
        int tok = n0 + (2 * mg + mt) * 16 + col;
        #pragma unroll
        for (int s = 0; s < 4; ++s) {
            const float* p = x + (size_t)tok * D_ + s * 32 + quad * 8;
            float4 u0 = *(const float4*)(p);
            float4 u1 = *(const float4*)(p + 4);
            ah[mt][s][0] = (_Float16)u0.x; ah[mt][s][1] = (_Float16)u0.y;
            ah[mt][s][2] = (_Float16)u0.z; ah[mt][s][3] = (_Float16)u0.w;
            ah[mt][s][4] = (_Float16)u1.x; ah[mt][s][5] = (_Float16)u1.y;
            ah[mt][s][6] = (_Float16)u1.z; ah[mt][s][7] = (_Float16)u1.w;
        }
    }

    unsigned k1[2][4], k2[2][4], k3[2][4];
    #pragma unroll
    for (int mt = 0; mt < 2; ++mt)
        #pragma unroll
        for (int r = 0; r < 4; ++r) {
            k1[mt][r] = 0xFFFFFFFFu; k2[mt][r] = 0xFFFFFFFFu; k3[mt][r] = 0xFFFFFFFFu;
        }

    __syncthreads();                          // e2s visible; nothing else in flight

    // ---- prologue: stage chunks 0,1 into slots 0,1 (2 ops each/wave) ----
    #pragma unroll
    for (int i = 0; i < 2; ++i) {
        int o = (w * 2 + i) * 512;
        gld16(Ef + o + L * 8, &Bs[0][o]);
    }
    #pragma unroll
    for (int i = 0; i < 2; ++i) {
        int o = (w * 2 + i) * 512;
        gld16(Ef + 8192 + o + L * 8, &Bs[1][o]);
    }

    #pragma unroll
    for (int q = 0; q < 16; ++q) {
        // outstanding here: chunk q (2 ops) + chunk q+1 (2 ops).
        // vmcnt(2) retires MY chunk-q loads; barrier => ALL waves' retired.
        if (q < 15) asm volatile("s_waitcnt vmcnt(2)" ::: "memory");
        else        asm volatile("s_waitcnt vmcnt(0)" ::: "memory");
        __builtin_amdgcn_s_barrier();
        asm volatile("" ::: "memory");

        const unsigned short* Bp = &Bs[q % 3][0];

        // ---- acc init = e2[code] + BIAS ----
        float evb[2];
        #pragma unroll
        for (int nn = 0; nn < 2; ++nn)
            evb[nn] = e2s[q * 64 + (2 * ng + nn) * 16 + col] + BIAS_;
        f32x4 acc[2][2];
        #pragma unroll
        for (int mt = 0; mt < 2; ++mt)
            #pragma unroll
            for (int nn = 0; nn < 2; ++nn)
                #pragma unroll
                for (int r = 0; r < 4; ++r)
                    acc[mt][nn][r] = evb[nn];

        // ---- 16 MFMA: 4 k-steps x 2 n-subs x 2 m-tiles ----
        #pragma unroll
        for (int s = 0; s < 4; ++s) {
            half8 bh[2];
            #pragma unroll
            for (int nn = 0; nn < 2; ++nn) {
                int off = (((2 * ng + nn) * 4 + s) * 64 + L) * 8;
                bh[nn] = *(const half8*)(Bp + off);
            }
            #pragma unroll
            for (int nn = 0; nn < 2; ++nn)
                #pragma unroll
                for (int mt = 0; mt < 2; ++mt)
                    acc[mt][nn] = __builtin_amdgcn_mfma_f32_16x16x32_f16(ah[mt][s], bh[nn], acc[mt][nn], 0, 0, 0);
        }

        // ---- clamp to [0.5,508] + packed-key top-3 insert ----
        #pragma unroll
        for (int nn = 0; nn < 2; ++nn) {
            unsigned cb = (unsigned)(q * 64 + (2 * ng + nn) * 16 + col);
            #pragma unroll
            for (int mt = 0; mt < 2; ++mt)
                #pragma unroll
                for (int r = 0; r < 4; ++r) {
                    float dc = fminf(fmaxf(acc[mt][nn][r], CLMIN_), CLMAX_);
                    unsigned key = (__float_as_uint(dc) & 0xFFFFFC00u) | cb;
                    unsigned m1 = umax32(k1[mt][r], key);
                    k1[mt][r]   = umin32(k1[mt][r], key);
                    unsigned m2 = umax32(k2[mt][r], m1);
                    k2[mt][r]   = umin32(k2[mt][r], m1);
                    k3[mt][r]   = umin32(k3[mt][r], m2);
                }
        }

        // ---- stage chunk q+2 into slot (q+2)%3 (WAR-safe) ----
        if (q < 14) {
            const unsigned short* src = Ef + (q + 2) * 8192;
            int sl = (q + 2) % 3;
            #pragma unroll
            for (int i = 0; i < 2; ++i) {
                int o = (w * 2 + i) * 512;
                gld16(src + o + L * 8, &Bs[sl][o]);
            }
        }
    }

    // ---- cross-lane merge of sorted triples over 16 cols ----
    __syncthreads();
    unsigned* mk1 = (unsigned*)&Bs[0][0];     // [128 tokens][2 halves] x 3
    unsigned* mk2 = mk1 + 256;
    unsigned* mk3 = mk2 + 256;

    #pragma unroll
    for (int mt = 0; mt < 2; ++mt) {
        #pragma unroll
        for (int r = 0; r < 4; ++r) {
            unsigned a = k1[mt][r], b = k2[mt][r], c = k3[mt][r];
            #pragma unroll
            for (int m = 1; m < 16; m <<= 1) {
                unsigned ao = (unsigned)__shfl_xor((int)a, m);
                unsigned bo = (unsigned)__shfl_xor((int)b, m);
                unsigned co = (unsigned)__shfl_xor((int)c, m);
                unsigned t1 = umax32(a, ao);
                a           = umin32(a, ao);
                unsigned s2 = umin32(b, bo);
                unsigned u  = umax32(t1, s2);
                b           = umin32(t1, s2);
                c           = umin32(u, umin32(c, co));
            }
            if (col == 0) {
                int tl = (2 * mg + mt) * 16 + quad * 4 + r;
                mk1[tl * 2 + ng] = a;
                mk2[tl * 2 + ng] = b;
                mk3[tl * 2 + ng] = c;
            }
        }
    }
    __syncthreads();
    if (tid < 128) {
        unsigned a1 = mk1[tid * 2], b1 = mk1[tid * 2 + 1];
        unsigned a2 = mk2[tid * 2], b2 = mk2[tid * 2 + 1];
        unsigned a3 = mk3[tid * 2], b3 = mk3[tid * 2 + 1];
        unsigned t1 = umax32(a1, b1);
        unsigned kk1 = umin32(a1, b1);
        unsigned s2 = umin32(a2, b2);
        unsigned kk2 = umin32(t1, s2);
        unsigned u  = umax32(t1, s2);
        unsigned kk3 = umin32(u, umin32(a3, b3));

        int i1 = (int)(kk1 & 1023u), i2 = (int)(kk2 & 1023u);
        float d1 = __uint_as_float(kk1 & 0xFFFFFC00u);
        float d2 = __uint_as_float(kk2 & 0xFFFFFC00u);
        float d3 = __uint_as_float(kk3 & 0xFFFFFC00u);
        int tok = n0 + tid;

        if (d3 - d1 < M2_) {
            // 3+ codes inside the uncertainty band: full exact rescan later
            code_i[tok] = i1;
            code_f[tok] = (float)i1;
            atomicAdd(cnt + i1, 1);
            int p = atomicAdd(rcnt, 1);
            rlist[p] = tok;
        } else {
            int win = i1;
            if (d2 - d1 < M1_) {
                // exact fp32 pair decision, inline (true argmin is i1 or i2)
                const float* xr = x  + (size_t)tok * D_;
                const float* ea = Et + (size_t)i1 * D_;
                const float* eb = Et + (size_t)i2 * D_;
                float s1 = 0.f, sB = 0.f;
                #pragma unroll 4
                for (int dd = 0; dd < D_; dd += 4) {
                    float4 xv = *(const float4*)(xr + dd);
                    float4 av = *(const float4*)(ea + dd);
                    float4 bv = *(const float4*)(eb + dd);
                    s1 = fmaf(xv.x, av.x, s1); s1 = fmaf(xv.y, av.y, s1);
                    s1 = fmaf(xv.z, av.z, s1); s1 = fmaf(xv.w, av.w, s1);
                    sB = fmaf(xv.x, bv.x, sB); sB = fmaf(xv.y, bv.y, sB);
                    sB = fmaf(xv.z, bv.z, sB); sB = fmaf(xv.w, bv.w, sB);
                }
                float ex1 = e2s[i1] - 2.f * s1;
                float ex2 = e2s[i2] - 2.f * sB;
                if (ex2 < ex1 || (ex2 == ex1 && i2 < i1)) win = i2;
            }
            code_i[tok] = win;
            code_f[tok] = (float)win;
            atomicAdd(cnt + win, 1);
        }
    }
}

// -------------------------------------------------------------------
// exact fp32 re-argmin for triple-ambiguous tokens. ILP depth 8:
// R15's 4-way unroll delivered only ~half the predicted gain -> the
// serial chain (dependent L2 load -> butterfly) is still the binding
// constraint. 8 named compile-time-indexed Et loads issued up front
// (no runtime-indexed arrays -> no scratch), 8 independent dot+reduce
// chains, halving dependent iterations 32 -> 16. Compare order
// ca<cb<...<ch preserves first-min (lowest index) semantics.
__launch_bounds__(256)
__global__ void k_fix(const float* __restrict__ x, const float* __restrict__ Et,
                      const float* __restrict__ e2, const int* __restrict__ rcnt,
                      const int* __restrict__ rlist, int* __restrict__ code_i,
                      float* __restrict__ code_f, int* __restrict__ cnt) {
    __shared__ float4 xs[32];
    __shared__ float  e2s[K_];
    __shared__ float  sd[8];
    __shared__ int    si[8];
    int tid = threadIdx.x;
    int lane = tid & 63, w = tid >> 6;
    int half = lane >> 5;
    int q32  = lane & 31;
    int slot = w * 2 + half;     // 0..7: codes c ≡ slot (mod 8)
    int nr = *rcnt;
    for (int i = tid; i < K_; i += 256) e2s[i] = e2[i];

    for (int it = blockIdx.x; it < nr; it += gridDim.x) {
        __syncthreads();                      // e2s ready / prev iter merged
        int tok = rlist[it];
        if (tid < 32) xs[tid] = ((const float4*)(x + (size_t)tok * D_))[tid];
        __syncthreads();
        float4 xv = xs[q32];
        float bd = INFINITY; int bb = 0;
        for (int c0 = 0; c0 < K_; c0 += 64) {
            int ca = c0 + slot;
            // 8 independent Et loads issued up front (break load-use chain)
            float4 ea = ((const float4*)(Et + (size_t)(ca     ) * D_))[q32];
            float4 eb = ((const float4*)(Et + (size_t)(ca +  8) * D_))[q32];
            float4 ec = ((const float4*)(Et + (size_t)(ca + 16) * D_))[q32];
            float4 ed = ((const float4*)(Et + (size_t)(ca + 24) * D_))[q32];
            float4 ee = ((const float4*)(Et + (size_t)(ca + 32) * D_))[q32];
            float4 ef = ((const float4*)(Et + (size_t)(ca + 40) * D_))[q32];
            float4 eg = ((const float4*)(Et + (size_t)(ca + 48) * D_))[q32];
            float4 eh = ((const float4*)(Et + (size_t)(ca + 56) * D_))[q32];
            float da = xv.x * ea.x + xv.y * ea.y + xv.z * ea.z + xv.w * ea.w;
            float db = xv.x * eb.x + xv.y * eb.y + xv.z * eb.z + xv.w * eb.w;
            float dc = xv.x * ec.x + xv.y * ec.y + xv.z * ec.z + xv.w * ec.w;
            float dd = xv.x * ed.x + xv.y * ed.y + xv.z * ed.z + xv.w * ed.w;
            float de = xv.x * ee.x + xv.y * ee.y + xv.z * ee.z + xv.w * ee.w;
            float df = xv.x * ef.x + xv.y * ef.y + xv.z * ef.z + xv.w * ef.w;
            float dg = xv.x * eg.x + xv.y * eg.y + xv.z * eg.z + xv.w * eg.w;
            float dh = xv.x * eh.x + xv.y * eh.y + xv.z * eh.z + xv.w * eh.w;
            #pragma unroll
            for (int m = 1; m <= 16; m <<= 1) {   // 8 interleaved reduce chains
                da += __shfl_xor(da, m);
                db += __shfl_xor(db, m);
                dc += __shfl_xor(dc, m);
                dd += __shfl_xor(dd, m);
                de += __shfl_xor(de, m);
                df += __shfl_xor(df, m);
                dg += __shfl_xor(dg, m);
                dh += __shfl_xor(dh, m);
            }
            float A  = e2s[ca     ] - 2.f * da;
            float B  = e2s[ca +  8] - 2.f * db;
            float C  = e2s[ca + 16] - 2.f * dc;
            float Dv = e2s[ca + 24] - 2.f * dd;
            float Ev = e2s[ca + 32] - 2.f * de;
            float Fv = e2s[ca + 40] - 2.f * df;
            float Gv = e2s[ca + 48] - 2.f * dg;
            float Hv = e2s[ca + 56] - 2.f * dh;
            if (A  < bd) { bd = A;  bb = ca;      }   // ascending code order =>
            if (B  < bd) { bd = B;  bb = ca +  8; }   // strict < keeps first-min
            if (C  < bd) { bd = C;  bb = ca + 16; }
            if (Dv < bd) { bd = Dv; bb = ca + 24; }
            if (Ev < bd) { bd = Ev; bb = ca + 32; }
            if (Fv < bd) { bd = Fv; bb = ca + 40; }
            if (Gv < bd) { bd = Gv; bb = ca + 48; }
            if (Hv < bd) { bd = Hv; bb = ca + 56; }
        }
        if (q32 == 0) { sd[slot] = bd; si[slot] = bb; }
        __syncthreads();
        if (tid == 0) {
            float fb = sd[0]; int fi = si[0];
            #pragma unroll
            for (int s = 1; s < 8; ++s) {
                if (sd[s] < fb || (sd[s] == fb && si[s] < fi)) { fb = sd[s]; fi = si[s]; }
            }
            int ob = code_i[tok];
            if (fi != ob) {
                code_i[tok] = fi;
                code_f[tok] = (float)fi;
                atomicAdd(cnt + ob, -1);
                atomicAdd(cnt + fi, 1);
            }
        }
    }
}

// -------------------------------------------------------------------
// Fused scan + scatter + DEQUANT/ST/ssq: runs after k_fix so codes are
// final. Phase 1: per-block redundant exclusive scan of cnt (LDS) +
// scatter of this block's 256 tokens (codes buffered in LDS).
// Phase 2: sequential-order dequant — 8 passes x 32 tokens, 8 threads
// per token x 16 dims (wave covers 4KB contiguous: coalesced x read +
// outq write; Et rows are L2-resident) + ssq block-reduce -> 1 atomic.
__launch_bounds__(256)
__global__ void k_scatter(const int* __restrict__ cnt, const int* __restrict__ code_i,
                          int* __restrict__ zc, int* __restrict__ order,
                          int* __restrict__ csort, const float* __restrict__ x,
                          const float* __restrict__ Et, float* __restrict__ outq,
                          float* __restrict__ ssqp) {
    __shared__ int sbase[1024];
    __shared__ int wtot[4];
    __shared__ int scode[256];
    __shared__ float wsf[4];
    int t = threadIdx.x;
    int lane = t & 63, wv = t >> 6;
    int c4[4];
    #pragma unroll
    for (int j = 0; j < 4; ++j) c4[j] = cnt[4 * t + j];
    int s = c4[0] + c4[1] + c4[2] + c4[3];
    int ps = s;
    #pragma unroll
    for (int m = 1; m < 64; m <<= 1) {
        int o = __shfl_up(ps, m);
        if (lane >= m) ps += o;
    }
    if (lane == 63) wtot[wv] = ps;
    __syncthreads();
    int woff = 0;
    for (int i = 0; i < 4; ++i) if (i < wv) woff += wtot[i];
    int run = woff + ps - s;
    #pragma unroll
    for (int j = 0; j < 4; ++j) {
        sbase[4 * t + j] = run;    // exclusive base of code 4t+j
        run += c4[j];
    }
    __syncthreads();

    int n = blockIdx.x * 256 + t;
    int c = code_i[n];
    scode[t] = c;
    int pos = sbase[c] + atomicAdd(zc + c, 1);
    order[pos] = n;
    csort[pos] = c;
    __syncthreads();

    // ---- phase 2: dequant/ST + ssq, sequential token order ----
    int tk8 = t >> 3;               // 0..31: token within pass
    int db  = (t & 7) * 16;         // dim base (4 x float4)
    float ssql = 0.f;
    #pragma unroll
    for (int pass = 0; pass < 8; ++pass) {
        int li  = pass * 32 + tk8;  // token slot in block
        int tok = blockIdx.x * 256 + li;
        int cc  = scode[li];
        const float* xr = x    + (size_t)tok * D_ + db;
        const float* er = Et   + (size_t)cc  * D_ + db;
        float*       qr = outq + (size_t)tok * D_ + db;
        #pragma unroll
        for (int k2 = 0; k2 < 4; ++k2) {
            float4 xv = *(const float4*)(xr + k2 * 4);
            float4 ev = *(const float4*)(er + k2 * 4);
            float4 qv;
            qv.x = xv.x + (ev.x - xv.x);      // reference fp32 rounding
            qv.y = xv.y + (ev.y - xv.y);
            qv.z = xv.z + (ev.z - xv.z);
            qv.w = xv.w + (ev.w - xv.w);
            *(float4*)(qr + k2 * 4) = qv;
            float t0 = qv.x - xv.x, t1 = qv.y - xv.y;
            float t2 = qv.z - xv.z, t3 = qv.w - xv.w;
            ssql += t0 * t0 + t1 * t1 + t2 * t2 + t3 * t3;
        }
    }
    #pragma unroll
    for (int off = 32; off > 0; off >>= 1) ssql += __shfl_down(ssql, off);
    if ((t & 63) == 0) wsf[t >> 6] = ssql;
    __syncthreads();
    if (t == 0) atomicAdd(ssqp, (wsf[0] + wsf[1]) + (wsf[2] + wsf[3]));
}

// -------------------------------------------------------------------
// PURE segment-sum: block i owns sorted slots [32i,32i+32) as TWO
// independent 16-slot halves, each with its own running-sum flush
// chain into part1[c][d].
__launch_bounds__(256)
__global__ void k_segsum(const float* __restrict__ x, const int* __restrict__ order,
                         const int* __restrict__ csort, float* __restrict__ part1) {
    __shared__ int sn[WSEG], sc[WSEG];
    int tid = threadIdx.x;
    int d = tid & 127;
    int h = tid >> 7;                       // half 0/1
    int i0 = blockIdx.x * WSEG;
    if (tid < WSEG) { sn[tid] = order[i0 + tid]; sc[tid] = csort[i0 + tid]; }
    __syncthreads();
    int s0 = h * 16;
    int cprev = sc[s0];
    float acc = 0.f;
    float xv = x[(size_t)sn[s0] * D_ + d];
    #pragma unroll 4
    for (int j = 0; j < 16; ++j) {
        int sj = s0 + j;
        float xn = (j < 15) ? x[(size_t)sn[sj + 1] * D_ + d] : 0.f;  // prefetch
        int c = sc[sj];
        if (c != cprev) {                      // wave-uniform branch
            atomicAdd(&part1[(size_t)cprev * D_ + d], acc);
            acc = 0.f;
            cprev = c;
        }
        acc += xv;
        xv = xn;
    }
    atomicAdd(&part1[(size_t)cprev * D_ + d], acc);
}

// -------------------------------------------------------------------
// fused stats + embed: each block redundantly reduces n; block 0 also
// writes out_ncs + out_diff. Then EMA mean + divide for its 256 elems.
__launch_bounds__(256)
__global__ void k_embed(const float* __restrict__ em, const float* __restrict__ part1,
                        const int* __restrict__ cnt, const float* __restrict__ csz,
                        const float* __restrict__ ssqp, float* __restrict__ out_nmean,
                        float* __restrict__ out_nemb, float* __restrict__ out_ncs,
                        float* __restrict__ out_diff) {
    int tid = threadIdx.x;
    __shared__ float red[256];

    // ---- n = sum_k ncs_k (redundant per block) ----
    float ls = 0.f;
    for (int j = tid; j < K_; j += 256) ls += csz[j] * DECAY_ + OMD_ * (float)cnt[j];
    red[tid] = ls;
    __syncthreads();
    for (int off = 128; off > 0; off >>= 1) {
        if (tid < off) red[tid] += red[tid + off];
        __syncthreads();
    }
    float n = red[0];
    __syncthreads();

    if (blockIdx.x == 0) {
        for (int j = tid; j < K_; j += 256)
            out_ncs[j] = csz[j] * DECAY_ + OMD_ * (float)cnt[j];
        if (tid == 0) *out_diff = VQC_ * ssqp[0] / (float)(N_ * D_);
    }

    int i = blockIdx.x * 256 + tid;           // over D*K, layout [D][K]
    int k = i & (K_ - 1);
    int d = i >> 10;
    float ncs_k = csz[k] * DECAY_ + OMD_ * (float)cnt[k];
    float csk = (ncs_k + EPS_) / (n + (float)K_ * EPS_) * n;
    float es = part1[(size_t)k * D_ + d];
    float nm = em[i] * DECAY_ + OMD_ * es;
    out_nmean[i] = nm;
    out_nemb[i]  = nm / csk;
}

// -------------------------------------------------------------------
extern "C" void kernel_launch(void* const* d_in, const int* in_sizes, int n_in,
                              void* d_out, int out_size, void* d_ws, size_t ws_size,
                              hipStream_t stream) {
    const float* x   = (const float*)d_in[0];   // [16,4096,128]
    const float* E   = (const float*)d_in[1];   // [128,1024]
    const float* csz = (const float*)d_in[2];   // [1024]
    const float* em  = (const float*)d_in[3];   // [128,1024]
    float* out = (float*)d_out;
    float* W   = (float*)d_ws;

    int*   code_i = (int*)(W + WOFF_CODE);
    float* e2     = W + WOFF_E2;
    int*   cnt    = (int*)(W + WOFF_CNT);
    float* ssqp   = W + WOFF_SSQ;
    int*   rcnt   = (int*)(W + WOFF_RCNT);
    int*   zc     = (int*)(W + WOFF_CURS);
    int*   order  = (int*)(W + WOFF_ORDER);
    float* Et     = W + WOFF_ET;
    float* part1  = W + WOFF_PART;
    int*   csort  = (int*)(W + WOFF_CSORT);
    int*   rlist  = (int*)(W + WOFF_RLIST);
    unsigned short* Ef = (unsigned short*)(W + WOFF_EF);

    k_prep<<<64, 256, 0, stream>>>(E, Et, Ef, e2, cnt, zc, part1);
    k_argmin_mfma<<<N_ / 128, 512, 0, stream>>>(x, Ef, e2, code_i,
                                                out + OOFF_CODE, cnt, rcnt, rlist, Et);
    k_fix<<<2048, 256, 0, stream>>>(x, Et, e2, rcnt, rlist, code_i, out + OOFF_CODE, cnt);
    k_scatter<<<N_ / 256, 256, 0, stream>>>(cnt, code_i, zc, order, csort,
                                            x, Et, out + OOFF_Q, ssqp);
    k_segsum<<<N_ / WSEG, 256, 0, stream>>>(x, order, csort, part1);
    k_embed<<<(D_ * K_) / 256, 256, 0, stream>>>(em, part1, cnt, csz, ssqp,
                                                 out + OOFF_NMEAN, out + OOFF_NEMB,
                                                 out + OOFF_NCS, out + OOFF_DIFF);
}